// Round 4
// baseline (448.078 us; speedup 1.0000x reference)
//
#include <hip/hip_runtime.h>
#include <type_traits>
#include <utility>

typedef unsigned short u16;
typedef unsigned int u32;
typedef __attribute__((ext_vector_type(8))) short short8;
typedef __attribute__((ext_vector_type(8))) __bf16 bhalf8;
typedef __attribute__((ext_vector_type(4))) short short4v;
typedef __attribute__((ext_vector_type(4))) __bf16 bhalf4;
typedef __attribute__((ext_vector_type(4))) float f32x4;
typedef __attribute__((ext_vector_type(16))) float f32x16;
typedef __attribute__((ext_vector_type(4))) unsigned short us4;

#define S_LEN 2048
#define NHEAD 32
#define HD 80
#define HDP 96
#define HID 2560
#define N3 7680
#define QK_SCALE 0.11180339887498949f  // 80^-0.5
#define LOG2E 1.4426950408889634f

// ---------- MFMA K=32 wrapper (hedge: builtin may take __bf16x8 or shortx8) ----------
template <typename T, typename = void> struct MfmaTakes : std::false_type {};
template <typename T>
struct MfmaTakes<T, std::void_t<decltype(__builtin_amdgcn_mfma_f32_16x16x32_bf16(
                       std::declval<T>(), std::declval<T>(), std::declval<f32x4>(), 0, 0, 0))>>
    : std::true_type {};

template <typename AB>
__device__ inline f32x4 mfma_raw(AB a, AB b, f32x4 c) {
  return __builtin_amdgcn_mfma_f32_16x16x32_bf16(a, b, c, 0, 0, 0);
}
using mfma_ab_t = std::conditional_t<MfmaTakes<bhalf8>::value, bhalf8, short8>;
__device__ inline f32x4 MFMA(short8 a, short8 b, f32x4 c) {
  return mfma_raw<mfma_ab_t>(__builtin_bit_cast(mfma_ab_t, a),
                             __builtin_bit_cast(mfma_ab_t, b), c);
}

// ---------- MFMA 32x32x16 wrapper ----------
template <typename T, typename = void> struct Mfma32Takes : std::false_type {};
template <typename T>
struct Mfma32Takes<T, std::void_t<decltype(__builtin_amdgcn_mfma_f32_32x32x16_bf16(
                       std::declval<T>(), std::declval<T>(), std::declval<f32x16>(), 0, 0, 0))>>
    : std::true_type {};
template <typename AB>
__device__ inline f32x16 mfma32_raw(AB a, AB b, f32x16 c) {
  return __builtin_amdgcn_mfma_f32_32x32x16_bf16(a, b, c, 0, 0, 0);
}
using mfma32_ab_t = std::conditional_t<Mfma32Takes<bhalf8>::value, bhalf8, short8>;
__device__ inline f32x16 MFMA32(short8 a, short8 b, f32x16 c) {
  return mfma32_raw<mfma32_ab_t>(__builtin_bit_cast(mfma32_ab_t, a),
                                 __builtin_bit_cast(mfma32_ab_t, b), c);
}

// ---------- MFMA K=16 wrapper (16x16x16 bf16), with emulation fallback ----------
#if defined(__has_builtin)
#if __has_builtin(__builtin_amdgcn_mfma_f32_16x16x16bf16_1k)
#define MFMA16_RAW(a, b, c) __builtin_amdgcn_mfma_f32_16x16x16bf16_1k(a, b, c, 0, 0, 0)
#define HAVE_MFMA16 1
#elif __has_builtin(__builtin_amdgcn_mfma_f32_16x16x16_bf16)
#define MFMA16_RAW(a, b, c) __builtin_amdgcn_mfma_f32_16x16x16_bf16(a, b, c, 0, 0, 0)
#define HAVE_MFMA16 1
#endif
#endif

#ifdef HAVE_MFMA16
template <typename T, typename = void> struct M16Takes : std::false_type {};
template <typename T>
struct M16Takes<T, std::void_t<decltype(MFMA16_RAW(std::declval<T>(), std::declval<T>(),
                                                   std::declval<f32x4>()))>> : std::true_type {};
using m16_t = std::conditional_t<M16Takes<bhalf4>::value, bhalf4, short4v>;
__device__ inline f32x4 MFMA16(short4v a, short4v b, f32x4 c) {
  return MFMA16_RAW(__builtin_bit_cast(m16_t, a), __builtin_bit_cast(m16_t, b), c);
}
#else
// Emulate K=16 via K=32 MFMA with zero upper k-half in BOTH operands.
__device__ inline f32x4 MFMA16(short4v a, short4v b, f32x4 c) {
  short8 a8 = {a[0], a[1], a[2], a[3], 0, 0, 0, 0};
  short8 b8 = {b[0], b[1], b[2], b[3], 0, 0, 0, 0};
  return MFMA(a8, b8, c);
}
#endif

__device__ inline float bf2f(u16 b) { return __uint_as_float(((u32)b) << 16); }
__device__ inline u16 f2bf(float f) {
  u32 u = __float_as_uint(f);
  u += 0x7fffu + ((u >> 16) & 1u);  // round-to-nearest-even
  return (u16)(u >> 16);
}

typedef __attribute__((address_space(1))) void as1_void;
typedef __attribute__((address_space(3))) void as3_void;

#if defined(__has_builtin)
#if __has_builtin(__builtin_amdgcn_global_load_lds)
#define HAVE_GLL 1
#endif
#endif

// Stage 16B/lane: global (per-lane addr) -> LDS (wave-uniform base + lane*16).
__device__ inline void stage16(const u16* g, u16* lds_base, int lane) {
#ifdef HAVE_GLL
  (void)lane;
  __builtin_amdgcn_global_load_lds((as1_void*)g, (as3_void*)lds_base, 16, 0, 0);
#else
  *(short8*)(lds_base + lane * 8) = *(const short8*)g;
#endif
}

__device__ inline void sched_barrier0() {
#if defined(__has_builtin)
#if __has_builtin(__builtin_amdgcn_sched_barrier)
  __builtin_amdgcn_sched_barrier(0);
#endif
#endif
}

// ---------- dtype detection: are the float tensors f32 or bf16 on device? ----------
__global__ __launch_bounds__(256) void detect_dtype(const u32* __restrict__ words,
                                                    int* __restrict__ flag) {
  __shared__ int red[256];
  int junk = 0;
  for (int i = threadIdx.x; i < 2048; i += 256) {
    u16 lo = (u16)(words[i] & 0xffffu);
    u32 e = (lo >> 7) & 0xffu;  // bf16 exponent field
    junk += (e >= 137u);        // |x| >= 1024, or NaN/Inf
  }
  red[threadIdx.x] = junk;
  __syncthreads();
  for (int s = 128; s > 0; s >>= 1) {
    if (threadIdx.x < s) red[threadIdx.x] += red[threadIdx.x + s];
    __syncthreads();
  }
  if (threadIdx.x == 0) flag[0] = (red[0] > 64) ? 1 : 0;  // 1 = f32, 0 = bf16
}

// ---------- hidden_states -> bf16 (contiguous) ----------
__global__ __launch_bounds__(256) void convert_hidden(const void* __restrict__ in,
                                                      u16* __restrict__ out, int n4,
                                                      const int* __restrict__ flagp) {
  const int f = *flagp;
  int i = blockIdx.x * 256 + threadIdx.x;
  if (i >= n4) return;
  if (f) {
    const float* inf = (const float*)in;
    us4 o;
#pragma unroll
    for (int j = 0; j < 4; ++j) o[j] = f2bf(inf[(size_t)i * 4 + j]);
    *(us4*)&out[(size_t)i * 4] = o;
  } else {
    *(us4*)&out[(size_t)i * 4] = *(const us4*)&((const u16*)in)[(size_t)i * 4];
  }
}

// ---------- transpose + convert: in [rows, cols] (f32 or bf16) -> out [cols, rows] bf16 ----------
__global__ __launch_bounds__(256) void transpose_conv(const void* __restrict__ in,
                                                      u16* __restrict__ out,
                                                      int rows, int cols,
                                                      const int* __restrict__ flagp) {
  __shared__ u16 tile[32][33];
  const int f = *flagp;
  int bx = blockIdx.x * 32;  // col base
  int by = blockIdx.y * 32;  // row base
  int tx = threadIdx.x & 31, ty = threadIdx.x >> 5;
#pragma unroll
  for (int i = ty; i < 32; i += 8) {
    size_t idx = (size_t)(by + i) * cols + bx + tx;
    tile[i][tx] = f ? f2bf(((const float*)in)[idx]) : ((const u16*)in)[idx];
  }
  __syncthreads();
#pragma unroll
  for (int i = ty; i < 32; i += 8)
    out[(size_t)(bx + i) * rows + by + tx] = tile[tx][i];
}

// ---------- V transpose: qkv[s][5120 + c] -> Vt[c][s] (c = h*80+d) ----------
__global__ __launch_bounds__(256) void vtrans(const u16* __restrict__ qkv,
                                              u16* __restrict__ Vt) {
  __shared__ u16 tile[32][33];
  int bx = blockIdx.x * 32;  // col base (0..2560)
  int by = blockIdx.y * 32;  // s base
  int tx = threadIdx.x & 31, ty = threadIdx.x >> 5;
#pragma unroll
  for (int i = ty; i < 32; i += 8)
    tile[i][tx] = qkv[(size_t)(by + i) * N3 + 2 * HID + bx + tx];
  __syncthreads();
#pragma unroll
  for (int i = ty; i < 32; i += 8)
    Vt[(size_t)(bx + i) * S_LEN + by + tx] = tile[tx][i];
}

// ---------- GEMM (128^2 m97-structure, kept for the small output GEMM) ----------
__global__ __launch_bounds__(256) void gemm_bt(const u16* __restrict__ A,
                                               const u16* __restrict__ Bt,
                                               void* __restrict__ C,
                                               int M, int N, int K,
                                               const int* __restrict__ flagp) {
  __shared__ u16 As[128 * 32];
  __shared__ u16 Bs[128 * 32];
  const int tid = threadIdx.x;
  const int w = tid >> 6, l = tid & 63;
  const int la = l & 15, qd = l >> 4;
  const int m0 = blockIdx.y * 128, n0 = blockIdx.x * 128;
  const int mw = (w >> 1) * 64, nw = (w & 1) * 64;
  const int rowA = l >> 2;
  const int segk = (l & 3) * 8;
  const int of32 = flagp ? *flagp : 0;
  f32x4 acc[4][4] = {};

  for (int k0 = 0; k0 < K; k0 += 32) {
#pragma unroll
    for (int j = 0; j < 2; ++j) {
      const int rb = w * 16 + j * 64;
      const u16* ga = A + (size_t)(m0 + rb + rowA) * K + k0 + segk;
      const u16* gb = Bt + (size_t)(n0 + rb + rowA) * K + k0 + segk;
      stage16(ga, &As[rb * 32], l);
      stage16(gb, &Bs[rb * 32], l);
    }
    __syncthreads();
    short8 af[4], bfr[4];
#pragma unroll
    for (int i = 0; i < 4; ++i)
      af[i] = *(const short8*)&As[(mw + i * 16 + la) * 32 + qd * 8];
#pragma unroll
    for (int j = 0; j < 4; ++j)
      bfr[j] = *(const short8*)&Bs[(nw + j * 16 + la) * 32 + qd * 8];
#pragma unroll
    for (int i = 0; i < 4; ++i)
#pragma unroll
      for (int j = 0; j < 4; ++j)
        acc[i][j] = MFMA(af[i], bfr[j], acc[i][j]);
    __syncthreads();
  }

#pragma unroll
  for (int i = 0; i < 4; ++i)
#pragma unroll
    for (int j = 0; j < 4; ++j) {
      const int r0 = m0 + mw + i * 16 + qd * 4;
      const int c0 = n0 + nw + j * 16 + la;
#pragma unroll
      for (int r = 0; r < 4; ++r) {
        if (of32)
          ((float*)C)[(size_t)(r0 + r) * N + c0] = acc[i][j][r];
        else
          ((u16*)C)[(size_t)(r0 + r) * N + c0] = f2bf(acc[i][j][r]);
      }
    }
}

// ---------- 256x256 counted-lgkm GEMM, 32x32x16 MFMA: A[M,K]*Bt[N,K] -> C bf16 ----------
// Same schedule skeleton as R3 (2 barriers/tile, counted lgkm gates, vmcnt(4)
// boundary), but 32x32x16 MFMA: half the MFMA instructions for the same FLOPs
// and a ~17% lower MFMA floor (m119: 2495 TF vs m06: 2075 TF ceiling). LDS
// fragment traffic is shape-invariant (24 x b128 per wave per tile).
// Fragment maps: A/B row(col)=lane&31, k=(lane>>5)*8+i;
// C/D col=lane&31, row=(reg&3)+8*(reg>>2)+4*(lane>>5) [m74/m101].
__global__ __launch_bounds__(512, 2) void gemm256(const u16* __restrict__ A,
                                                  const u16* __restrict__ Bt,
                                                  u16* __restrict__ C,
                                                  int M, int N, int K) {
  __shared__ u16 As[2][256 * 64];  // 64 KiB
  __shared__ u16 Bs[2][256 * 64];  // 64 KiB
  const int tid = threadIdx.x;
  const int w = tid >> 6, l = tid & 63;
  const int r31 = l & 31, kh = l >> 5, x7 = l & 7;
  const int wr = w >> 2, wc = w & 3;

  const int nbx = gridDim.x;
  const int nwg = nbx * gridDim.y;
  int lin = blockIdx.y * nbx + blockIdx.x;
  if ((nwg & 7) == 0) lin = (lin & 7) * (nwg >> 3) + (lin >> 3);
  const int m0 = (lin / nbx) * 256, n0 = (lin % nbx) * 256;
  const int NT = K >> 6;

  // swizzled 16B-slot offsets (u16 units) for the 4 k-steps; slot = ks*2+kh,
  // XORed with row&7 (= x7 since row = ...+ (l&31)); matches staging's gsw.
  const int sxx[4] = {((0 + kh) ^ x7) * 8, ((2 + kh) ^ x7) * 8,
                      ((4 + kh) ^ x7) * 8, ((6 + kh) ^ x7) * 8};
  const int gsw = ((tid & 7) ^ ((tid >> 3) & 7)) * 8;  // inverse swizzle, global side

  f32x16 acc[4][2] = {};

  // half-tile stream: s = 4*tile + {0:B.h0, 1:B.h1, 2:A.h0, 3:A.h1}; 2 gll each.
  auto issue = [&](int s) {
    if (s >= NT * 4) return;
    const int kt = s >> 2, part = s & 3, buf = kt & 1;
    const int h = part & 1;
    const u16* G = (part >= 2) ? A : Bt;
    const int b0 = (part >= 2) ? m0 : n0;
    u16* L = ((part >= 2) ? &As[buf][0] : &Bs[buf][0]) + h * 8192;
    const int k0 = kt << 6;
#pragma unroll
    for (int q = 0; q < 2; ++q) {
      const int row = h * 128 + q * 64 + (tid >> 3);
      const u16* g = G + (size_t)(b0 + row) * K + k0 + gsw;
      stage16(g, L + (q * 512 + w * 64) * 8, l);
    }
  };

  auto readA = [&](int buf, int g, short8(&af)[2][4]) {
    const u16* base = &As[buf][0];
#pragma unroll
    for (int mi = 0; mi < 2; ++mi) {
      const int ro = (wr * 128 + (g * 2 + mi) * 32 + r31) * 64;
#pragma unroll
      for (int ks = 0; ks < 4; ++ks)
        af[mi][ks] = *(const short8*)(base + ro + sxx[ks]);
    }
  };
  auto readB = [&](int buf, int nj, short8(&bf)[4]) {
    const u16* base = &Bs[buf][0];
    const int ro = (wc * 64 + nj * 32 + r31) * 64;
#pragma unroll
    for (int ks = 0; ks < 4; ++ks)
      bf[ks] = *(const short8*)(base + ro + sxx[ks]);
  };
  auto quad = [&](short8(&af)[2][4], short8(&bf)[4], int g, int nj) {
#pragma unroll
    for (int ks = 0; ks < 4; ++ks)
#pragma unroll
      for (int mi = 0; mi < 2; ++mi)
        acc[g * 2 + mi][nj] = MFMA32(af[mi][ks], bf[ks], acc[g * 2 + mi][nj]);
  };

  // prologue: B0.h0,B0.h1,A0.h0,A0.h1,B1.h0,B1.h1 (12 loads); vmcnt(4) ->
  // A0,B0 landed, B1's 4 loads in flight (steady-state invariant).
#pragma unroll
  for (int s = 0; s < 6; ++s) issue(s);
  asm volatile("s_waitcnt vmcnt(4)" ::: "memory");
  __builtin_amdgcn_s_barrier();

  for (int t = 0; t < NT; ++t) {
    const int buf = t & 1;
    short8 af01[2][4], af23[2][4], bf0[4], bf1[4];
    // ---- issue all fragment reads for this tile (order pinned) ----
    readA(buf, 0, af01);  // 8 ds_read_b128
    sched_barrier0();
    readB(buf, 0, bf0);   // 4
    sched_barrier0();
    readB(buf, 1, bf1);   // 4
    sched_barrier0();
    // A(t+1) -> other buffer: prev tile's A-readers drained at its lgkm(0)
    // before its ending barrier, so no race.
    issue(4 * t + 6);
    issue(4 * t + 7);
    // ---- burst 1: need af01+bf0 (first 12 of 16) -> lgkm(4) ----
    asm volatile("s_waitcnt lgkmcnt(4)" ::: "memory");
    sched_barrier0();
    readA(buf, 1, af23);  // 8 more reads; drain under bursts 1-2
    sched_barrier0();
    __builtin_amdgcn_s_setprio(1);
    quad(af01, bf0, 0, 0);
    __builtin_amdgcn_s_setprio(0);
    // ---- burst 2: need bf1 (all but af23's 8) -> lgkm(8) ----
    asm volatile("s_waitcnt lgkmcnt(8)" ::: "memory");
    sched_barrier0();
    __builtin_amdgcn_s_setprio(1);
    quad(af01, bf1, 0, 1);
    __builtin_amdgcn_s_setprio(0);
    // ---- every wave past lgkm(8) => its B-reads done; sync then overwrite B ----
    __builtin_amdgcn_s_barrier();
    issue(4 * t + 8);  // B.h0(t+2) -> Bs[buf]
    issue(4 * t + 9);  // B.h1(t+2)
    // ---- burst 3: need af23 -> lgkm(0) ----
    asm volatile("s_waitcnt lgkmcnt(0)" ::: "memory");
    sched_barrier0();
    __builtin_amdgcn_s_setprio(1);
    quad(af23, bf0, 1, 0);
    quad(af23, bf1, 1, 1);
    __builtin_amdgcn_s_setprio(0);
    // ---- boundary: A(t+1)+B(t+1) complete, B(t+2) stays in flight ----
    asm volatile("s_waitcnt vmcnt(4)" ::: "memory");
    __builtin_amdgcn_s_barrier();
  }

  // epilogue: C[m0+wr*128+mi*32+(r&3)+8*(r>>2)+4*kh][n0+wc*64+nj*32+r31]
#pragma unroll
  for (int mi = 0; mi < 4; ++mi)
#pragma unroll
    for (int nj = 0; nj < 2; ++nj) {
      const int rb = m0 + wr * 128 + mi * 32 + 4 * kh;
      const int c0 = n0 + wc * 64 + nj * 32 + r31;
#pragma unroll
      for (int r = 0; r < 16; ++r) {
        const int row = rb + (r & 3) + 8 * (r >> 2);
        C[(size_t)row * N + c0] = f2bf(acc[mi][nj][r]);
      }
    }
}

// ---------- RoPE prep ----------
// Q -> Qh row-major [NH][S][96] (bf16, zero-padded).
// K -> Kt TILED: per (head, 64-key tile): [12 slots][64 rows][8 u16]; slot s
// holds cols [8s, 8s+8). This makes attn's K staging fully linear (coalesced
// global_load_lds) and the MFMA fragment reads lane-contiguous (bank-conflict
// free: la stride = 16 B).
__global__ __launch_bounds__(256) void rope_prep(const u16* __restrict__ qkv,
                                                 const int* __restrict__ pos,
                                                 u16* __restrict__ Qh,
                                                 u16* __restrict__ Kt) {
  const int s = blockIdx.x;
  const int h = blockIdx.y * 4 + (threadIdx.x >> 6);
  const int t = threadIdx.x & 63;
  const size_t qin = (size_t)s * N3 + h * HD;
  const size_t kin = qin + HID;
  const size_t ob = ((size_t)h * S_LEN + s) * HDP;
  const size_t kb = ((size_t)(h * 32) + (s >> 6)) * 6144 + (size_t)(s & 63) * 8;
  if (t < 32) {
    const float p = (float)pos[s];
    const float inv = exp2f(-(float)t * (13.287712379549449f / 32.0f));
    const float ang = p * inv;
    const float cs = cosf(ang), sn = sinf(ang);
    float x1 = bf2f(qkv[qin + t]), x2 = bf2f(qkv[qin + t + 32]);
    Qh[ob + t] = f2bf(x1 * cs - x2 * sn);
    Qh[ob + t + 32] = f2bf(x2 * cs + x1 * sn);
    x1 = bf2f(qkv[kin + t]);
    x2 = bf2f(qkv[kin + t + 32]);
    Kt[kb + (size_t)(t >> 3) * 512 + (t & 7)] = f2bf(x1 * cs - x2 * sn);
    const int d2 = t + 32;
    Kt[kb + (size_t)(d2 >> 3) * 512 + (d2 & 7)] = f2bf(x2 * cs + x1 * sn);
  } else if (t < 48) {
    const int d = t + 32;  // 64..79 pass-through
    Qh[ob + d] = qkv[qin + d];
    Kt[kb + (size_t)(d >> 3) * 512 + (d & 7)] = qkv[kin + d];
  } else {
    const int d = t + 32;  // 80..95 zero pad
    Qh[ob + d] = 0;
    Kt[kb + (size_t)(d >> 3) * 512 + (d & 7)] = 0;
  }
}

// ---------- Fused causal+ALiBi flash attention, pair-balanced ----------
__global__ __launch_bounds__(512) void attn_fused(const u16* __restrict__ Qh,
                                                  const u16* __restrict__ Kt,
                                                  const u16* __restrict__ Vt,
                                                  u16* __restrict__ AO) {
  __shared__ u16 Ks[2][768 * 8];  // 2 x 12288 B (12 slots x 64 rows x 16 B)
  __shared__ u16 Vs[2][640 * 8];  // 2 x 10240 B (swizzled columns)
  const int tid = threadIdx.x, w = tid >> 6, l = tid & 63;
  const int la = l & 15, qd = l >> 4;
  const int h = blockIdx.y;
  const int p = blockIdx.x;        // pair index 0..7
  const int q0A = (15 - p) * 128;  // long segment first
  const int q0B = p * 128;
  const int nItA = (q0A >> 6) + 2;
  const int nItB = (q0B >> 6) + 2;
  const size_t hS = (size_t)h * S_LEN;

  short8 qfA[3], qfB[3];
#pragma unroll
  for (int c = 0; c < 3; ++c) {
    qfA[c] = *(const short8*)&Qh[(hS + q0A + w * 16 + la) * HDP + c * 32 + qd * 8];
    qfB[c] = *(const short8*)&Qh[(hS + q0B + w * 16 + la) * HDP + c * 32 + qd * 8];
  }

  const float slope2 = exp2f(-0.25f * (float)(h + 1)) * LOG2E;
  const float scl2 = QK_SCALE * LOG2E;
  float m_i = -1e30f, l_i = 0.f;
  f32x4 acc[5] = {};

  const u16* gK = Kt + (size_t)h * 32 * 6144;
  const u16* gV = Vt + (size_t)h * HD * S_LEN;

  // Issue (async) staging of key-tile kt_g into buffer buf. K is linear; V is
  // gathered with the inverse column swizzle (read side is conflict-free).
  auto stage = [&](int kt_g, int buf) {
    const u16* gkt = gK + (size_t)kt_g * 6144;
    stage16(gkt + (size_t)(w * 64 + l) * 8, &Ks[buf][(w * 64) * 8], l);
    if (w < 4)
      stage16(gkt + (size_t)(512 + w * 64 + l) * 8, &Ks[buf][(512 + w * 64) * 8], l);
    const u16* gv = gV + (kt_g << 6);
    {
      const int c = w * 64 + l;
      const int row = c >> 3, seg = c & 7;
      const int gcol = ((seg - (row & 7)) & 7) * 8;
      stage16(gv + (size_t)row * S_LEN + gcol, &Vs[buf][(w * 64) * 8], l);
    }
    if (w < 2) {
      const int c = 512 + w * 64 + l;
      const int row = c >> 3, seg = c & 7;
      const int gcol = ((seg - (row & 7)) & 7) * 8;
      stage16(gv + (size_t)row * S_LEN + gcol, &Vs[buf][(512 + w * 64) * 8], l);
    }
  };

  int g = 0;  // global iteration counter (buffer parity across segments)
  stage(0, 0);

  auto run_seg = [&](const short8(&qf)[3], int q0, int nIt, bool more) {
    const int qb = q0 + w * 16;
    const int q = qb + la;
    for (int it = 0; it < nIt; ++it, ++g) {
      const int buf = g & 1;
      __syncthreads();  // stage(g) complete; all waves done with buf^1
      if (it + 1 < nIt) stage(it + 1, buf ^ 1);
      else if (more) stage(0, buf ^ 1);  // restart key stream for next segment
      const int k0 = it << 6;
      if (k0 >= qb + 16) continue;  // wave-uniform skip of fully-masked tiles

      // --- S^T tiles from LDS (lane-contiguous reads of the tiled K) ---
      f32x4 st[4];
#pragma unroll
      for (int kt = 0; kt < 4; ++kt) {
        short8 kf[3];
#pragma unroll
        for (int c = 0; c < 3; ++c)
          kf[c] = *(const short8*)&Ks[buf][((c * 4 + qd) * 64 + kt * 16 + la) * 8];
        f32x4 z = {};
#pragma unroll
        for (int c = 0; c < 3; ++c) z = MFMA(kf[c], qf[c], z);
        st[kt] = z;
      }

      // --- mask + scale (log2 domain) ---
      const float base = (float)(k0 + qd * 4 - q);  // rel = base + (kt*16 + r)
      float mloc = -1e30f;
      if (k0 + 64 <= qb + 1) {  // tile fully unmasked for every lane of wave
#pragma unroll
        for (int kt = 0; kt < 4; ++kt)
#pragma unroll
          for (int r = 0; r < 4; ++r) {
            const float rel = base + (float)(kt * 16 + r);
            const float v = st[kt][r] * scl2 + slope2 * rel;
            st[kt][r] = v;
            mloc = fmaxf(mloc, v);
          }
      } else {
#pragma unroll
        for (int kt = 0; kt < 4; ++kt)
#pragma unroll
          for (int r = 0; r < 4; ++r) {
            const float rel = base + (float)(kt * 16 + r);
            const float v = (rel <= 0.f) ? st[kt][r] * scl2 + slope2 * rel : -1e30f;
            st[kt][r] = v;
            mloc = fmaxf(mloc, v);
          }
      }
      mloc = fmaxf(mloc, __shfl_xor(mloc, 16));
      mloc = fmaxf(mloc, __shfl_xor(mloc, 32));

      // --- defer-max (T13): rescale only when the max actually grew ---
      if (!__all(mloc - m_i <= 8.0f)) {
        const float nm = fmaxf(m_i, mloc);
        const float al = exp2f(m_i - nm);
        m_i = nm;
        l_i *= al;
#pragma unroll
        for (int dt = 0; dt < 5; ++dt) acc[dt] *= al;
      }

      float ps = 0.f;
      short4v pf[4];
#pragma unroll
      for (int kt = 0; kt < 4; ++kt) {
        short4v pk;
#pragma unroll
        for (int r = 0; r < 4; ++r) {
          const float pv = exp2f(st[kt][r] - m_i);
          ps += pv;
          pk[r] = (short)f2bf(pv);
        }
        pf[kt] = pk;
      }
      ps += __shfl_xor(ps, 16);
      ps += __shfl_xor(ps, 32);
      l_i += ps;

      // --- PV from LDS (swizzled, conflict-free b64): O^T += V^T * P^T ---
      const int cb = qd * 4 + ((la & 7) << 3);
#pragma unroll
      for (int dt = 0; dt < 5; ++dt) {
        const int vrow = (dt * 16 + la) * 64;
#pragma unroll
        for (int kt = 0; kt < 4; ++kt) {
          const short4v vf = *(const short4v*)&Vs[buf][vrow + ((kt * 16 + cb) & 63)];
          acc[dt] = MFMA16(vf, pf[kt], acc[dt]);
        }
      }
    }
    // --- epilogue for this segment: lane holds O^T[d=dt*16+qd*4+r][q] ---
    const float inv = 1.0f / l_i;
    const size_t row = (size_t)q;
#pragma unroll
    for (int dt = 0; dt < 5; ++dt) {
      us4 o;
#pragma unroll
      for (int r = 0; r < 4; ++r) o[r] = f2bf(acc[dt][r] * inv);
      *(us4*)&AO[row * HID + h * HD + dt * 16 + qd * 4] = o;
    }
    m_i = -1e30f;
    l_i = 0.f;
#pragma unroll
    for (int dt = 0; dt < 5; ++dt) acc[dt] = f32x4{};
  };

  run_seg(qfA, q0A, nItA, true);
  run_seg(qfB, q0B, nItB, false);
}

extern "C" void kernel_launch(void* const* d_in, const int* in_sizes, int n_in,
                              void* d_out, int out_size, void* d_ws, size_t ws_size,
                              hipStream_t stream) {
  const int* pos = (const int*)d_in[0];
  const void* hidden = d_in[1];
  const void* w_qkv = d_in[2];
  const void* w_out = d_in[3];
  u16* ws = (u16*)d_ws;

  // ws layout (u16 elements). Hb dead after GEMM1 -> Vt aliases it (same size).
  // WtQ dead after GEMM1 -> Qh/Kh/AO alias into it (17.8M <= 19.66M).
  u16* Hb = ws;                                  //  5,242,880
  u16* WtQ = Hb + (size_t)S_LEN * HID;           // 19,660,800
  u16* WtO = WtQ + (size_t)N3 * HID;             //  6,553,600
  u16* qkv = WtO + (size_t)HID * HID;            // 15,728,640
  int* flag = (int*)(qkv + (size_t)S_LEN * N3);  // 1 int
  u16* Vt = Hb;                                  //  5,242,880 (alias)
  u16* Qh = WtQ;                                 //  6,291,456 (alias)
  u16* Kh = Qh + (size_t)NHEAD * S_LEN * HDP;    //  6,291,456 (alias, tiled layout)
  u16* AO = Kh + (size_t)NHEAD * S_LEN * HDP;    //  5,242,880 (alias)

  detect_dtype<<<1, 256, 0, stream>>>((const u32*)hidden, flag);
  convert_hidden<<<(S_LEN * HID / 4 + 255) / 256, 256, 0, stream>>>(hidden, Hb,
                                                                    S_LEN * HID / 4, flag);
  transpose_conv<<<dim3(N3 / 32, HID / 32), 256, 0, stream>>>(w_qkv, WtQ, HID, N3, flag);
  transpose_conv<<<dim3(HID / 32, HID / 32), 256, 0, stream>>>(w_out, WtO, HID, HID, flag);
  gemm256<<<dim3(N3 / 256, S_LEN / 256), 512, 0, stream>>>(Hb, WtQ, qkv, S_LEN, N3, HID);
  vtrans<<<dim3(HID / 32, S_LEN / 32), 256, 0, stream>>>(qkv, Vt);
  rope_prep<<<dim3(S_LEN, NHEAD / 4), 256, 0, stream>>>(qkv, pos, Qh, Kh);
  attn_fused<<<dim3(8, NHEAD), 512, 0, stream>>>(Qh, Kh, Vt, AO);
  gemm_bt<<<dim3(HID / 128, S_LEN / 128), 256, 0, stream>>>(AO, WtO, d_out, S_LEN, HID, HID,
                                                            flag);
}

// Round 5
// 426.829 us; speedup vs baseline: 1.0498x; 1.0498x over previous
//
#include <hip/hip_runtime.h>
#include <type_traits>
#include <utility>

typedef unsigned short u16;
typedef unsigned int u32;
typedef __attribute__((ext_vector_type(8))) short short8;
typedef __attribute__((ext_vector_type(8))) __bf16 bhalf8;
typedef __attribute__((ext_vector_type(4))) short short4v;
typedef __attribute__((ext_vector_type(4))) __bf16 bhalf4;
typedef __attribute__((ext_vector_type(4))) float f32x4;
typedef __attribute__((ext_vector_type(4))) unsigned short us4;

#define S_LEN 2048
#define NHEAD 32
#define HD 80
#define HDP 96
#define HID 2560
#define N3 7680
#define QK_SCALE 0.11180339887498949f  // 80^-0.5
#define LOG2E 1.4426950408889634f

// ---------- MFMA K=32 wrapper (hedge: builtin may take __bf16x8 or shortx8) ----------
template <typename T, typename = void> struct MfmaTakes : std::false_type {};
template <typename T>
struct MfmaTakes<T, std::void_t<decltype(__builtin_amdgcn_mfma_f32_16x16x32_bf16(
                       std::declval<T>(), std::declval<T>(), std::declval<f32x4>(), 0, 0, 0))>>
    : std::true_type {};

template <typename AB>
__device__ inline f32x4 mfma_raw(AB a, AB b, f32x4 c) {
  return __builtin_amdgcn_mfma_f32_16x16x32_bf16(a, b, c, 0, 0, 0);
}
using mfma_ab_t = std::conditional_t<MfmaTakes<bhalf8>::value, bhalf8, short8>;
__device__ inline f32x4 MFMA(short8 a, short8 b, f32x4 c) {
  return mfma_raw<mfma_ab_t>(__builtin_bit_cast(mfma_ab_t, a),
                             __builtin_bit_cast(mfma_ab_t, b), c);
}

// ---------- MFMA K=16 wrapper (16x16x16 bf16), with emulation fallback ----------
#if defined(__has_builtin)
#if __has_builtin(__builtin_amdgcn_mfma_f32_16x16x16bf16_1k)
#define MFMA16_RAW(a, b, c) __builtin_amdgcn_mfma_f32_16x16x16bf16_1k(a, b, c, 0, 0, 0)
#define HAVE_MFMA16 1
#elif __has_builtin(__builtin_amdgcn_mfma_f32_16x16x16_bf16)
#define MFMA16_RAW(a, b, c) __builtin_amdgcn_mfma_f32_16x16x16_bf16(a, b, c, 0, 0, 0)
#define HAVE_MFMA16 1
#endif
#endif

#ifdef HAVE_MFMA16
template <typename T, typename = void> struct M16Takes : std::false_type {};
template <typename T>
struct M16Takes<T, std::void_t<decltype(MFMA16_RAW(std::declval<T>(), std::declval<T>(),
                                                   std::declval<f32x4>()))>> : std::true_type {};
using m16_t = std::conditional_t<M16Takes<bhalf4>::value, bhalf4, short4v>;
__device__ inline f32x4 MFMA16(short4v a, short4v b, f32x4 c) {
  return MFMA16_RAW(__builtin_bit_cast(m16_t, a), __builtin_bit_cast(m16_t, b), c);
}
#else
// Emulate K=16 via K=32 MFMA with zero upper k-half in BOTH operands.
__device__ inline f32x4 MFMA16(short4v a, short4v b, f32x4 c) {
  short8 a8 = {a[0], a[1], a[2], a[3], 0, 0, 0, 0};
  short8 b8 = {b[0], b[1], b[2], b[3], 0, 0, 0, 0};
  return MFMA(a8, b8, c);
}
#endif

__device__ inline float bf2f(u16 b) { return __uint_as_float(((u32)b) << 16); }
__device__ inline u16 f2bf(float f) {
  u32 u = __float_as_uint(f);
  u += 0x7fffu + ((u >> 16) & 1u);  // round-to-nearest-even
  return (u16)(u >> 16);
}

typedef __attribute__((address_space(1))) void as1_void;
typedef __attribute__((address_space(3))) void as3_void;

#if defined(__has_builtin)
#if __has_builtin(__builtin_amdgcn_global_load_lds)
#define HAVE_GLL 1
#endif
#endif

// Stage 16B/lane: global (per-lane addr) -> LDS (wave-uniform base + lane*16).
__device__ inline void stage16(const u16* g, u16* lds_base, int lane) {
#ifdef HAVE_GLL
  (void)lane;
  __builtin_amdgcn_global_load_lds((as1_void*)g, (as3_void*)lds_base, 16, 0, 0);
#else
  *(short8*)(lds_base + lane * 8) = *(const short8*)g;
#endif
}

__device__ inline void sched_barrier0() {
#if defined(__has_builtin)
#if __has_builtin(__builtin_amdgcn_sched_barrier)
  __builtin_amdgcn_sched_barrier(0);
#endif
#endif
}

// ---------- dtype detection: are the float tensors f32 or bf16 on device? ----------
__global__ __launch_bounds__(256) void detect_dtype(const u32* __restrict__ words,
                                                    int* __restrict__ flag) {
  __shared__ int red[256];
  int junk = 0;
  for (int i = threadIdx.x; i < 2048; i += 256) {
    u16 lo = (u16)(words[i] & 0xffffu);
    u32 e = (lo >> 7) & 0xffu;  // bf16 exponent field
    junk += (e >= 137u);        // |x| >= 1024, or NaN/Inf
  }
  red[threadIdx.x] = junk;
  __syncthreads();
  for (int s = 128; s > 0; s >>= 1) {
    if (threadIdx.x < s) red[threadIdx.x] += red[threadIdx.x + s];
    __syncthreads();
  }
  if (threadIdx.x == 0) flag[0] = (red[0] > 64) ? 1 : 0;  // 1 = f32, 0 = bf16
}

// ---------- hidden_states -> bf16 (contiguous) ----------
__global__ __launch_bounds__(256) void convert_hidden(const void* __restrict__ in,
                                                      u16* __restrict__ out, int n4,
                                                      const int* __restrict__ flagp) {
  const int f = *flagp;
  int i = blockIdx.x * 256 + threadIdx.x;
  if (i >= n4) return;
  if (f) {
    const float* inf = (const float*)in;
    us4 o;
#pragma unroll
    for (int j = 0; j < 4; ++j) o[j] = f2bf(inf[(size_t)i * 4 + j]);
    *(us4*)&out[(size_t)i * 4] = o;
  } else {
    *(us4*)&out[(size_t)i * 4] = *(const us4*)&((const u16*)in)[(size_t)i * 4];
  }
}

// ---------- vectorized 64x64 transpose (+optional f32->bf16 convert) ----------
// in: [*, istride] (f32 if *flagp else bf16), logical block at (by,bx).
// out[bx+c][by+r] = in[by+r][ioff+bx+c], out bf16 with row stride ostride.
// 16B/8B global loads, 8B global stores. LDS tile [64][66]: row stride 33
// dwords -> column reads hit 2 lanes/bank (free, m136); 4B LDS writes keep
// alignment (132B row stride is not 8B-aligned).
__global__ __launch_bounds__(256) void transpose64(const void* __restrict__ in,
                                                   u16* __restrict__ out,
                                                   int istride, int ioff, int ostride,
                                                   const int* __restrict__ flagp) {
  __shared__ u16 tile[64][66];
  const int f = flagp ? *flagp : 0;
  const int bx = blockIdx.x * 64, by = blockIdx.y * 64;
  const int tx4 = (threadIdx.x & 15) * 4, ty = threadIdx.x >> 4;  // ty 0..15
#pragma unroll
  for (int i = 0; i < 4; ++i) {
    const int row = ty + i * 16;
    const size_t idx = (size_t)(by + row) * istride + ioff + bx + tx4;
    us4 v;
    if (f) {
      const f32x4 x = *(const f32x4*)&((const float*)in)[idx];
#pragma unroll
      for (int j = 0; j < 4; ++j) v[j] = f2bf(x[j]);
    } else {
      v = *(const us4*)&((const u16*)in)[idx];
    }
    *(u32*)&tile[row][tx4] = (u32)v[0] | ((u32)v[1] << 16);
    *(u32*)&tile[row][tx4 + 2] = (u32)v[2] | ((u32)v[3] << 16);
  }
  __syncthreads();
#pragma unroll
  for (int i = 0; i < 4; ++i) {
    const int oc = ty + i * 16;
    us4 o;
#pragma unroll
    for (int j = 0; j < 4; ++j) o[j] = tile[tx4 + j][oc];
    *(us4*)&out[(size_t)(bx + oc) * ostride + by + tx4] = o;
  }
}

// ---------- GEMM (128^2 m97-structure, kept for the small output GEMM) ----------
__global__ __launch_bounds__(256) void gemm_bt(const u16* __restrict__ A,
                                               const u16* __restrict__ Bt,
                                               void* __restrict__ C,
                                               int M, int N, int K,
                                               const int* __restrict__ flagp) {
  __shared__ u16 As[128 * 32];
  __shared__ u16 Bs[128 * 32];
  const int tid = threadIdx.x;
  const int w = tid >> 6, l = tid & 63;
  const int la = l & 15, qd = l >> 4;
  const int m0 = blockIdx.y * 128, n0 = blockIdx.x * 128;
  const int mw = (w >> 1) * 64, nw = (w & 1) * 64;
  const int rowA = l >> 2;
  const int segk = (l & 3) * 8;
  const int of32 = flagp ? *flagp : 0;
  f32x4 acc[4][4] = {};

  for (int k0 = 0; k0 < K; k0 += 32) {
#pragma unroll
    for (int j = 0; j < 2; ++j) {
      const int rb = w * 16 + j * 64;
      const u16* ga = A + (size_t)(m0 + rb + rowA) * K + k0 + segk;
      const u16* gb = Bt + (size_t)(n0 + rb + rowA) * K + k0 + segk;
      stage16(ga, &As[rb * 32], l);
      stage16(gb, &Bs[rb * 32], l);
    }
    __syncthreads();
    short8 af[4], bfr[4];
#pragma unroll
    for (int i = 0; i < 4; ++i)
      af[i] = *(const short8*)&As[(mw + i * 16 + la) * 32 + qd * 8];
#pragma unroll
    for (int j = 0; j < 4; ++j)
      bfr[j] = *(const short8*)&Bs[(nw + j * 16 + la) * 32 + qd * 8];
#pragma unroll
    for (int i = 0; i < 4; ++i)
#pragma unroll
      for (int j = 0; j < 4; ++j)
        acc[i][j] = MFMA(af[i], bfr[j], acc[i][j]);
    __syncthreads();
  }

#pragma unroll
  for (int i = 0; i < 4; ++i)
#pragma unroll
    for (int j = 0; j < 4; ++j) {
      const int r0 = m0 + mw + i * 16 + qd * 4;
      const int c0 = n0 + nw + j * 16 + la;
#pragma unroll
      for (int r = 0; r < 4; ++r) {
        if (of32)
          ((float*)C)[(size_t)(r0 + r) * N + c0] = acc[i][j][r];
        else
          ((u16*)C)[(size_t)(r0 + r) * N + c0] = f2bf(acc[i][j][r]);
      }
    }
}

// ---------- 256x256 counted-lgkm GEMM: A[M,K]*Bt[N,K] -> C[M,N] bf16 ----------
// R3-verified version (92.4 us, 0 bank conflicts). 2 barriers per K-tile,
// counted lgkmcnt gates so LDS fragment drains overlap MFMA bursts; A(t+1)
// gll at tile top (other buffer), mid-tile barrier after every wave's B-reads
// drained (lgkm(8) precedes it) then B(t+2) gll into the CURRENT buffer,
// boundary vmcnt(4) (entering tile t exactly B(t+1)'s 4 loads in flight).
__global__ __launch_bounds__(512, 2) void gemm256(const u16* __restrict__ A,
                                                  const u16* __restrict__ Bt,
                                                  u16* __restrict__ C,
                                                  int M, int N, int K) {
  __shared__ u16 As[2][256 * 64];  // 64 KiB
  __shared__ u16 Bs[2][256 * 64];  // 64 KiB
  const int tid = threadIdx.x;
  const int w = tid >> 6, l = tid & 63, la = l & 15, qd = l >> 4;
  const int wr = w >> 2, wc = w & 3;

  const int nbx = gridDim.x;
  const int nwg = nbx * gridDim.y;
  int lin = blockIdx.y * nbx + blockIdx.x;
  if ((nwg & 7) == 0) lin = (lin & 7) * (nwg >> 3) + (lin >> 3);
  const int m0 = (lin / nbx) * 256, n0 = (lin % nbx) * 256;
  const int NT = K >> 6;

  const int sx0 = (qd ^ (la & 7)) * 8;        // swizzled 16B-slot (u16 units), kk=0
  const int sx1 = ((4 + qd) ^ (la & 7)) * 8;  // kk=1
  const int gsw = ((tid & 7) ^ ((tid >> 3) & 7)) * 8;  // inverse swizzle, global side

  f32x4 acc[8][4] = {};

  // half-tile stream: s = 4*tile + {0:B.h0, 1:B.h1, 2:A.h0, 3:A.h1}; 2 gll each.
  auto issue = [&](int s) {
    if (s >= NT * 4) return;
    const int kt = s >> 2, part = s & 3, buf = kt & 1;
    const int h = part & 1;
    const u16* G = (part >= 2) ? A : Bt;
    const int b0 = (part >= 2) ? m0 : n0;
    u16* L = ((part >= 2) ? &As[buf][0] : &Bs[buf][0]) + h * 8192;
    const int k0 = kt << 6;
#pragma unroll
    for (int q = 0; q < 2; ++q) {
      const int row = h * 128 + q * 64 + (tid >> 3);
      const u16* g = G + (size_t)(b0 + row) * K + k0 + gsw;
      stage16(g, L + (q * 512 + w * 64) * 8, l);
    }
  };

  auto readA = [&](int buf, int mh, short8(&af)[4][2]) {
    const u16* base = &As[buf][0];
#pragma unroll
    for (int i = 0; i < 4; ++i) {
      const int ro = (wr * 128 + mh * 64 + i * 16 + la) * 64;
      af[i][0] = *(const short8*)(base + ro + sx0);
      af[i][1] = *(const short8*)(base + ro + sx1);
    }
  };
  auto readB = [&](int buf, int nh, short8(&bf)[2][2]) {
    const u16* base = &Bs[buf][0];
#pragma unroll
    for (int j = 0; j < 2; ++j) {
      const int ro = (wc * 64 + nh * 32 + j * 16 + la) * 64;
      bf[j][0] = *(const short8*)(base + ro + sx0);
      bf[j][1] = *(const short8*)(base + ro + sx1);
    }
  };
  auto quad = [&](short8(&af)[4][2], short8(&bf)[2][2], int mh, int nh) {
#pragma unroll
    for (int kk = 0; kk < 2; ++kk)
#pragma unroll
      for (int i = 0; i < 4; ++i)
#pragma unroll
        for (int jj = 0; jj < 2; ++jj)
          acc[mh * 4 + i][nh * 2 + jj] =
              MFMA(af[i][kk], bf[jj][kk], acc[mh * 4 + i][nh * 2 + jj]);
  };

  // prologue: B0.h0,B0.h1,A0.h0,A0.h1,B1.h0,B1.h1 (12 loads); vmcnt(4) ->
  // A0,B0 landed, B1's 4 loads in flight (steady-state invariant).
#pragma unroll
  for (int s = 0; s < 6; ++s) issue(s);
  asm volatile("s_waitcnt vmcnt(4)" ::: "memory");
  __builtin_amdgcn_s_barrier();

  for (int t = 0; t < NT; ++t) {
    const int buf = t & 1;
    short8 af[4][2], af2[4][2], bf0[2][2], bf1[2][2];
    // ---- issue all fragment reads for this tile (order pinned) ----
    readA(buf, 0, af);   // 8 ds_read_b128
    sched_barrier0();
    readB(buf, 0, bf0);  // 4
    sched_barrier0();
    readB(buf, 1, bf1);  // 4
    sched_barrier0();
    // A(t+1) -> other buffer: prev tile's A-readers drained at its lgkm(0)
    // before its ending barrier, so no race.
    issue(4 * t + 6);
    issue(4 * t + 7);
    // ---- burst 1: need af+bf0 (first 12 of 16) -> lgkm(4) ----
    asm volatile("s_waitcnt lgkmcnt(4)" ::: "memory");
    sched_barrier0();
    readA(buf, 1, af2);  // 8 more reads; drain under bursts 1-2
    sched_barrier0();
    __builtin_amdgcn_s_setprio(1);
    quad(af, bf0, 0, 0);
    __builtin_amdgcn_s_setprio(0);
    // ---- burst 2: need bf1 (all but af2's 8) -> lgkm(8) ----
    asm volatile("s_waitcnt lgkmcnt(8)" ::: "memory");
    sched_barrier0();
    __builtin_amdgcn_s_setprio(1);
    quad(af, bf1, 0, 1);
    __builtin_amdgcn_s_setprio(0);
    // ---- every wave past lgkm(8) => its B-reads done; sync then overwrite B ----
    __builtin_amdgcn_s_barrier();
    issue(4 * t + 8);  // B.h0(t+2) -> Bs[buf]
    issue(4 * t + 9);  // B.h1(t+2)
    // ---- burst 3: need af2 -> lgkm(0) ----
    asm volatile("s_waitcnt lgkmcnt(0)" ::: "memory");
    sched_barrier0();
    __builtin_amdgcn_s_setprio(1);
    quad(af2, bf0, 1, 0);
    quad(af2, bf1, 1, 1);
    __builtin_amdgcn_s_setprio(0);
    // ---- boundary: A(t+1)+B(t+1) complete, B(t+2) stays in flight ----
    asm volatile("s_waitcnt vmcnt(4)" ::: "memory");
    __builtin_amdgcn_s_barrier();
  }

  // epilogue: C[m0+wr*128+i*16+qd*4+r][n0+wc*64+j*16+la]
#pragma unroll
  for (int i = 0; i < 8; ++i)
#pragma unroll
    for (int j = 0; j < 4; ++j) {
      const int r0 = m0 + wr * 128 + i * 16 + qd * 4;
      const int c0 = n0 + wc * 64 + j * 16 + la;
#pragma unroll
      for (int r = 0; r < 4; ++r)
        C[(size_t)(r0 + r) * N + c0] = f2bf(acc[i][j][r]);
    }
}

// ---------- RoPE prep ----------
// Q -> Qh row-major [NH][S][96] (bf16, zero-padded).
// K -> Kt TILED: per (head, 64-key tile): [12 slots][64 rows][8 u16]; slot s
// holds cols [8s, 8s+8). This makes attn's K staging fully linear (coalesced
// global_load_lds) and the MFMA fragment reads lane-contiguous (bank-conflict
// free: la stride = 16 B).
__global__ __launch_bounds__(256) void rope_prep(const u16* __restrict__ qkv,
                                                 const int* __restrict__ pos,
                                                 u16* __restrict__ Qh,
                                                 u16* __restrict__ Kt) {
  const int s = blockIdx.x;
  const int h = blockIdx.y * 4 + (threadIdx.x >> 6);
  const int t = threadIdx.x & 63;
  const size_t qin = (size_t)s * N3 + h * HD;
  const size_t kin = qin + HID;
  const size_t ob = ((size_t)h * S_LEN + s) * HDP;
  const size_t kb = ((size_t)(h * 32) + (s >> 6)) * 6144 + (size_t)(s & 63) * 8;
  if (t < 32) {
    const float p = (float)pos[s];
    const float inv = exp2f(-(float)t * (13.287712379549449f / 32.0f));
    const float ang = p * inv;
    const float cs = cosf(ang), sn = sinf(ang);
    float x1 = bf2f(qkv[qin + t]), x2 = bf2f(qkv[qin + t + 32]);
    Qh[ob + t] = f2bf(x1 * cs - x2 * sn);
    Qh[ob + t + 32] = f2bf(x2 * cs + x1 * sn);
    x1 = bf2f(qkv[kin + t]);
    x2 = bf2f(qkv[kin + t + 32]);
    Kt[kb + (size_t)(t >> 3) * 512 + (t & 7)] = f2bf(x1 * cs - x2 * sn);
    const int d2 = t + 32;
    Kt[kb + (size_t)(d2 >> 3) * 512 + (d2 & 7)] = f2bf(x2 * cs + x1 * sn);
  } else if (t < 48) {
    const int d = t + 32;  // 64..79 pass-through
    Qh[ob + d] = qkv[qin + d];
    Kt[kb + (size_t)(d >> 3) * 512 + (d & 7)] = qkv[kin + d];
  } else {
    const int d = t + 32;  // 80..95 zero pad
    Qh[ob + d] = 0;
    Kt[kb + (size_t)(d >> 3) * 512 + (d & 7)] = 0;
  }
}

// ---------- Fused causal+ALiBi flash attention, pair-balanced ----------
__global__ __launch_bounds__(512) void attn_fused(const u16* __restrict__ Qh,
                                                  const u16* __restrict__ Kt,
                                                  const u16* __restrict__ Vt,
                                                  u16* __restrict__ AO) {
  __shared__ u16 Ks[2][768 * 8];  // 2 x 12288 B (12 slots x 64 rows x 16 B)
  __shared__ u16 Vs[2][640 * 8];  // 2 x 10240 B (swizzled columns)
  const int tid = threadIdx.x, w = tid >> 6, l = tid & 63;
  const int la = l & 15, qd = l >> 4;
  const int h = blockIdx.y;
  const int p = blockIdx.x;        // pair index 0..7
  const int q0A = (15 - p) * 128;  // long segment first
  const int q0B = p * 128;
  const int nItA = (q0A >> 6) + 2;
  const int nItB = (q0B >> 6) + 2;
  const size_t hS = (size_t)h * S_LEN;

  short8 qfA[3], qfB[3];
#pragma unroll
  for (int c = 0; c < 3; ++c) {
    qfA[c] = *(const short8*)&Qh[(hS + q0A + w * 16 + la) * HDP + c * 32 + qd * 8];
    qfB[c] = *(const short8*)&Qh[(hS + q0B + w * 16 + la) * HDP + c * 32 + qd * 8];
  }

  const float slope2 = exp2f(-0.25f * (float)(h + 1)) * LOG2E;
  const float scl2 = QK_SCALE * LOG2E;
  float m_i = -1e30f, l_i = 0.f;
  f32x4 acc[5] = {};

  const u16* gK = Kt + (size_t)h * 32 * 6144;
  const u16* gV = Vt + (size_t)h * HD * S_LEN;

  // Issue (async) staging of key-tile kt_g into buffer buf. K is linear; V is
  // gathered with the inverse column swizzle (read side is conflict-free).
  auto stage = [&](int kt_g, int buf) {
    const u16* gkt = gK + (size_t)kt_g * 6144;
    stage16(gkt + (size_t)(w * 64 + l) * 8, &Ks[buf][(w * 64) * 8], l);
    if (w < 4)
      stage16(gkt + (size_t)(512 + w * 64 + l) * 8, &Ks[buf][(512 + w * 64) * 8], l);
    const u16* gv = gV + (kt_g << 6);
    {
      const int c = w * 64 + l;
      const int row = c >> 3, seg = c & 7;
      const int gcol = ((seg - (row & 7)) & 7) * 8;
      stage16(gv + (size_t)row * S_LEN + gcol, &Vs[buf][(w * 64) * 8], l);
    }
    if (w < 2) {
      const int c = 512 + w * 64 + l;
      const int row = c >> 3, seg = c & 7;
      const int gcol = ((seg - (row & 7)) & 7) * 8;
      stage16(gv + (size_t)row * S_LEN + gcol, &Vs[buf][(512 + w * 64) * 8], l);
    }
  };

  int g = 0;  // global iteration counter (buffer parity across segments)
  stage(0, 0);

  auto run_seg = [&](const short8(&qf)[3], int q0, int nIt, bool more) {
    const int qb = q0 + w * 16;
    const int q = qb + la;
    for (int it = 0; it < nIt; ++it, ++g) {
      const int buf = g & 1;
      __syncthreads();  // stage(g) complete; all waves done with buf^1
      if (it + 1 < nIt) stage(it + 1, buf ^ 1);
      else if (more) stage(0, buf ^ 1);  // restart key stream for next segment
      const int k0 = it << 6;
      if (k0 >= qb + 16) continue;  // wave-uniform skip of fully-masked tiles

      // --- S^T tiles from LDS (lane-contiguous reads of the tiled K) ---
      f32x4 st[4];
#pragma unroll
      for (int kt = 0; kt < 4; ++kt) {
        short8 kf[3];
#pragma unroll
        for (int c = 0; c < 3; ++c)
          kf[c] = *(const short8*)&Ks[buf][((c * 4 + qd) * 64 + kt * 16 + la) * 8];
        f32x4 z = {};
#pragma unroll
        for (int c = 0; c < 3; ++c) z = MFMA(kf[c], qf[c], z);
        st[kt] = z;
      }

      // --- mask + scale (log2 domain) ---
      const float base = (float)(k0 + qd * 4 - q);  // rel = base + (kt*16 + r)
      float mloc = -1e30f;
      if (k0 + 64 <= qb + 1) {  // tile fully unmasked for every lane of wave
#pragma unroll
        for (int kt = 0; kt < 4; ++kt)
#pragma unroll
          for (int r = 0; r < 4; ++r) {
            const float rel = base + (float)(kt * 16 + r);
            const float v = st[kt][r] * scl2 + slope2 * rel;
            st[kt][r] = v;
            mloc = fmaxf(mloc, v);
          }
      } else {
#pragma unroll
        for (int kt = 0; kt < 4; ++kt)
#pragma unroll
          for (int r = 0; r < 4; ++r) {
            const float rel = base + (float)(kt * 16 + r);
            const float v = (rel <= 0.f) ? st[kt][r] * scl2 + slope2 * rel : -1e30f;
            st[kt][r] = v;
            mloc = fmaxf(mloc, v);
          }
      }
      mloc = fmaxf(mloc, __shfl_xor(mloc, 16));
      mloc = fmaxf(mloc, __shfl_xor(mloc, 32));

      // --- defer-max (T13): rescale only when the max actually grew ---
      if (!__all(mloc - m_i <= 8.0f)) {
        const float nm = fmaxf(m_i, mloc);
        const float al = exp2f(m_i - nm);
        m_i = nm;
        l_i *= al;
#pragma unroll
        for (int dt = 0; dt < 5; ++dt) acc[dt] *= al;
      }

      float ps = 0.f;
      short4v pf[4];
#pragma unroll
      for (int kt = 0; kt < 4; ++kt) {
        short4v pk;
#pragma unroll
        for (int r = 0; r < 4; ++r) {
          const float pv = exp2f(st[kt][r] - m_i);
          ps += pv;
          pk[r] = (short)f2bf(pv);
        }
        pf[kt] = pk;
      }
      ps += __shfl_xor(ps, 16);
      ps += __shfl_xor(ps, 32);
      l_i += ps;

      // --- PV from LDS (swizzled, conflict-free b64): O^T += V^T * P^T ---
      const int cb = qd * 4 + ((la & 7) << 3);
#pragma unroll
      for (int dt = 0; dt < 5; ++dt) {
        const int vrow = (dt * 16 + la) * 64;
#pragma unroll
        for (int kt = 0; kt < 4; ++kt) {
          const short4v vf = *(const short4v*)&Vs[buf][vrow + ((kt * 16 + cb) & 63)];
          acc[dt] = MFMA16(vf, pf[kt], acc[dt]);
        }
      }
    }
    // --- epilogue for this segment: lane holds O^T[d=dt*16+qd*4+r][q] ---
    const float inv = 1.0f / l_i;
    const size_t row = (size_t)q;
#pragma unroll
    for (int dt = 0; dt < 5; ++dt) {
      us4 o;
#pragma unroll
      for (int r = 0; r < 4; ++r) o[r] = f2bf(acc[dt][r] * inv);
      *(us4*)&AO[row * HID + h * HD + dt * 16 + qd * 4] = o;
    }
    m_i = -1e30f;
    l_i = 0.f;
#pragma unroll
    for (int dt = 0; dt < 5; ++dt) acc[dt] = f32x4{};
  };

  run_seg(qfA, q0A, nItA, true);
  run_seg(qfB, q0B, nItB, false);
}

extern "C" void kernel_launch(void* const* d_in, const int* in_sizes, int n_in,
                              void* d_out, int out_size, void* d_ws, size_t ws_size,
                              hipStream_t stream) {
  const int* pos = (const int*)d_in[0];
  const void* hidden = d_in[1];
  const void* w_qkv = d_in[2];
  const void* w_out = d_in[3];
  u16* ws = (u16*)d_ws;

  // ws layout (u16 elements). Hb dead after GEMM1 -> Vt aliases it (same size).
  // WtQ dead after GEMM1 -> Qh/Kh/AO alias into it (17.8M <= 19.66M).
  u16* Hb = ws;                                  //  5,242,880
  u16* WtQ = Hb + (size_t)S_LEN * HID;           // 19,660,800
  u16* WtO = WtQ + (size_t)N3 * HID;             //  6,553,600
  u16* qkv = WtO + (size_t)HID * HID;            // 15,728,640
  int* flag = (int*)(qkv + (size_t)S_LEN * N3);  // 1 int
  u16* Vt = Hb;                                  //  5,242,880 (alias)
  u16* Qh = WtQ;                                 //  6,291,456 (alias)
  u16* Kh = Qh + (size_t)NHEAD * S_LEN * HDP;    //  6,291,456 (alias, tiled layout)
  u16* AO = Kh + (size_t)NHEAD * S_LEN * HDP;    //  5,242,880 (alias)

  detect_dtype<<<1, 256, 0, stream>>>((const u32*)hidden, flag);
  convert_hidden<<<(S_LEN * HID / 4 + 255) / 256, 256, 0, stream>>>(hidden, Hb,
                                                                    S_LEN * HID / 4, flag);
  // w_qkv [HID][N3] -> WtQ [N3][HID]
  transpose64<<<dim3(N3 / 64, HID / 64), 256, 0, stream>>>(w_qkv, WtQ, N3, 0, HID, flag);
  // w_out [HID][HID] -> WtO [HID][HID]
  transpose64<<<dim3(HID / 64, HID / 64), 256, 0, stream>>>(w_out, WtO, HID, 0, HID, flag);
  gemm256<<<dim3(N3 / 256, S_LEN / 256), 512, 0, stream>>>(Hb, WtQ, qkv, S_LEN, N3, HID);
  // qkv[s][2*HID + c] -> Vt[c][s]
  transpose64<<<dim3(HID / 64, S_LEN / 64), 256, 0, stream>>>(qkv, Vt, N3, 2 * HID, S_LEN,
                                                              nullptr);
  rope_prep<<<dim3(S_LEN, NHEAD / 4), 256, 0, stream>>>(qkv, pos, Qh, Kh);
  attn_fused<<<dim3(8, NHEAD), 512, 0, stream>>>(Qh, Kh, Vt, AO);
  gemm_bt<<<dim3(HID / 128, S_LEN / 128), 256, 0, stream>>>(AO, WtO, d_out, S_LEN, HID, HID,
                                                            flag);
}

// Round 6
// 389.441 us; speedup vs baseline: 1.1506x; 1.0960x over previous
//
#include <hip/hip_runtime.h>
#include <type_traits>
#include <utility>

typedef unsigned short u16;
typedef unsigned int u32;
typedef __attribute__((ext_vector_type(8))) short short8;
typedef __attribute__((ext_vector_type(8))) __bf16 bhalf8;
typedef __attribute__((ext_vector_type(4))) short short4v;
typedef __attribute__((ext_vector_type(4))) __bf16 bhalf4;
typedef __attribute__((ext_vector_type(4))) float f32x4;
typedef __attribute__((ext_vector_type(4))) unsigned short us4;

#define S_LEN 2048
#define NHEAD 32
#define HD 80
#define HDP 96
#define HID 2560
#define N3 7680
#define QK_SCALE 0.11180339887498949f  // 80^-0.5
#define LOG2E 1.4426950408889634f

// ---------- MFMA K=32 wrapper (hedge: builtin may take __bf16x8 or shortx8) ----------
template <typename T, typename = void> struct MfmaTakes : std::false_type {};
template <typename T>
struct MfmaTakes<T, std::void_t<decltype(__builtin_amdgcn_mfma_f32_16x16x32_bf16(
                       std::declval<T>(), std::declval<T>(), std::declval<f32x4>(), 0, 0, 0))>>
    : std::true_type {};

template <typename AB>
__device__ inline f32x4 mfma_raw(AB a, AB b, f32x4 c) {
  return __builtin_amdgcn_mfma_f32_16x16x32_bf16(a, b, c, 0, 0, 0);
}
using mfma_ab_t = std::conditional_t<MfmaTakes<bhalf8>::value, bhalf8, short8>;
__device__ inline f32x4 MFMA(short8 a, short8 b, f32x4 c) {
  return mfma_raw<mfma_ab_t>(__builtin_bit_cast(mfma_ab_t, a),
                             __builtin_bit_cast(mfma_ab_t, b), c);
}

// ---------- MFMA K=16 wrapper (16x16x16 bf16), with emulation fallback ----------
#if defined(__has_builtin)
#if __has_builtin(__builtin_amdgcn_mfma_f32_16x16x16bf16_1k)
#define MFMA16_RAW(a, b, c) __builtin_amdgcn_mfma_f32_16x16x16bf16_1k(a, b, c, 0, 0, 0)
#define HAVE_MFMA16 1
#elif __has_builtin(__builtin_amdgcn_mfma_f32_16x16x16_bf16)
#define MFMA16_RAW(a, b, c) __builtin_amdgcn_mfma_f32_16x16x16_bf16(a, b, c, 0, 0, 0)
#define HAVE_MFMA16 1
#endif
#endif

#ifdef HAVE_MFMA16
template <typename T, typename = void> struct M16Takes : std::false_type {};
template <typename T>
struct M16Takes<T, std::void_t<decltype(MFMA16_RAW(std::declval<T>(), std::declval<T>(),
                                                   std::declval<f32x4>()))>> : std::true_type {};
using m16_t = std::conditional_t<M16Takes<bhalf4>::value, bhalf4, short4v>;
__device__ inline f32x4 MFMA16(short4v a, short4v b, f32x4 c) {
  return MFMA16_RAW(__builtin_bit_cast(m16_t, a), __builtin_bit_cast(m16_t, b), c);
}
#else
// Emulate K=16 via K=32 MFMA with zero upper k-half in BOTH operands.
__device__ inline f32x4 MFMA16(short4v a, short4v b, f32x4 c) {
  short8 a8 = {a[0], a[1], a[2], a[3], 0, 0, 0, 0};
  short8 b8 = {b[0], b[1], b[2], b[3], 0, 0, 0, 0};
  return MFMA(a8, b8, c);
}
#endif

__device__ inline float bf2f(u16 b) { return __uint_as_float(((u32)b) << 16); }
__device__ inline u16 f2bf(float f) {
  u32 u = __float_as_uint(f);
  u += 0x7fffu + ((u >> 16) & 1u);  // round-to-nearest-even
  return (u16)(u >> 16);
}

typedef __attribute__((address_space(1))) void as1_void;
typedef __attribute__((address_space(3))) void as3_void;

#if defined(__has_builtin)
#if __has_builtin(__builtin_amdgcn_global_load_lds)
#define HAVE_GLL 1
#endif
#endif

// Stage 16B/lane: global (per-lane addr) -> LDS (wave-uniform base + lane*16).
__device__ inline void stage16(const u16* g, u16* lds_base, int lane) {
#ifdef HAVE_GLL
  (void)lane;
  __builtin_amdgcn_global_load_lds((as1_void*)g, (as3_void*)lds_base, 16, 0, 0);
#else
  *(short8*)(lds_base + lane * 8) = *(const short8*)g;
#endif
}

__device__ inline void sched_barrier0() {
#if defined(__has_builtin)
#if __has_builtin(__builtin_amdgcn_sched_barrier)
  __builtin_amdgcn_sched_barrier(0);
#endif
#endif
}

// ---------- dtype detection: are the float tensors f32 or bf16 on device? ----------
__global__ __launch_bounds__(256) void detect_dtype(const u32* __restrict__ words,
                                                    int* __restrict__ flag) {
  __shared__ int red[256];
  int junk = 0;
  for (int i = threadIdx.x; i < 2048; i += 256) {
    u16 lo = (u16)(words[i] & 0xffffu);
    u32 e = (lo >> 7) & 0xffu;  // bf16 exponent field
    junk += (e >= 137u);        // |x| >= 1024, or NaN/Inf
  }
  red[threadIdx.x] = junk;
  __syncthreads();
  for (int s = 128; s > 0; s >>= 1) {
    if (threadIdx.x < s) red[threadIdx.x] += red[threadIdx.x + s];
    __syncthreads();
  }
  if (threadIdx.x == 0) flag[0] = (red[0] > 64) ? 1 : 0;  // 1 = f32, 0 = bf16
}

// ---------- hidden_states -> bf16 (contiguous) ----------
__global__ __launch_bounds__(256) void convert_hidden(const void* __restrict__ in,
                                                      u16* __restrict__ out, int n4,
                                                      const int* __restrict__ flagp) {
  const int f = *flagp;
  int i = blockIdx.x * 256 + threadIdx.x;
  if (i >= n4) return;
  if (f) {
    const float* inf = (const float*)in;
    us4 o;
#pragma unroll
    for (int j = 0; j < 4; ++j) o[j] = f2bf(inf[(size_t)i * 4 + j]);
    *(us4*)&out[(size_t)i * 4] = o;
  } else {
    *(us4*)&out[(size_t)i * 4] = *(const us4*)&((const u16*)in)[(size_t)i * 4];
  }
}

// ---------- vectorized 64x64 transpose (+optional f32->bf16 convert) ----------
__global__ __launch_bounds__(256) void transpose64(const void* __restrict__ in,
                                                   u16* __restrict__ out,
                                                   int istride, int ioff, int ostride,
                                                   const int* __restrict__ flagp) {
  __shared__ u16 tile[64][66];
  const int f = flagp ? *flagp : 0;
  const int bx = blockIdx.x * 64, by = blockIdx.y * 64;
  const int tx4 = (threadIdx.x & 15) * 4, ty = threadIdx.x >> 4;  // ty 0..15
#pragma unroll
  for (int i = 0; i < 4; ++i) {
    const int row = ty + i * 16;
    const size_t idx = (size_t)(by + row) * istride + ioff + bx + tx4;
    us4 v;
    if (f) {
      const f32x4 x = *(const f32x4*)&((const float*)in)[idx];
#pragma unroll
      for (int j = 0; j < 4; ++j) v[j] = f2bf(x[j]);
    } else {
      v = *(const us4*)&((const u16*)in)[idx];
    }
    *(u32*)&tile[row][tx4] = (u32)v[0] | ((u32)v[1] << 16);
    *(u32*)&tile[row][tx4 + 2] = (u32)v[2] | ((u32)v[3] << 16);
  }
  __syncthreads();
#pragma unroll
  for (int i = 0; i < 4; ++i) {
    const int oc = ty + i * 16;
    us4 o;
#pragma unroll
    for (int j = 0; j < 4; ++j) o[j] = tile[tx4 + j][oc];
    *(us4*)&out[(size_t)(bx + oc) * ostride + by + tx4] = o;
  }
}

// ---------- 128x128 counted-lgkm GEMM (output GEMM): A[M,K]*Bt[N,K] -> C ----------
// R3-verified gemm256 schedule cloned at 128^2: 4 waves (2Mx2N, per-wave 64x64),
// BK=64, 64 KiB LDS -> 2 blocks/CU, grid 320 blocks (vs 80 at 256^2: fill wins).
// Same swizzle, same gll stream, gates re-derived for 4-read groups.
__global__ __launch_bounds__(256, 2) void gemm128c(const u16* __restrict__ A,
                                                   const u16* __restrict__ Bt,
                                                   void* __restrict__ C,
                                                   int M, int N, int K,
                                                   const int* __restrict__ flagp) {
  __shared__ u16 As[2][128 * 64];  // 16 KiB each buf
  __shared__ u16 Bs[2][128 * 64];
  const int tid = threadIdx.x;
  const int w = tid >> 6, l = tid & 63, la = l & 15, qd = l >> 4;
  const int wr = w >> 1, wc = w & 1;
  const int of32 = flagp ? *flagp : 0;

  const int nbx = gridDim.x;
  const int nwg = nbx * gridDim.y;
  int lin = blockIdx.y * nbx + blockIdx.x;
  if ((nwg & 7) == 0) lin = (lin & 7) * (nwg >> 3) + (lin >> 3);
  const int m0 = (lin / nbx) * 128, n0 = (lin % nbx) * 128;
  const int NT = K >> 6;

  const int sx0 = (qd ^ (la & 7)) * 8;        // swizzled 16B-slot, kk=0
  const int sx1 = ((4 + qd) ^ (la & 7)) * 8;  // kk=1
  const int gsw = ((tid & 7) ^ ((tid >> 3) & 7)) * 8;  // inverse swizzle, global side

  f32x4 acc[4][4] = {};

  // half-tile stream: s = 4*tile + {0:B.h0, 1:B.h1, 2:A.h0, 3:A.h1}; 2 gll each.
  auto issue = [&](int s) {
    if (s >= NT * 4) return;
    const int kt = s >> 2, part = s & 3, buf = kt & 1;
    const int h = part & 1;
    const u16* G = (part >= 2) ? A : Bt;
    const int b0 = (part >= 2) ? m0 : n0;
    u16* L = ((part >= 2) ? &As[buf][0] : &Bs[buf][0]) + h * 4096;
    const int k0 = kt << 6;
#pragma unroll
    for (int q = 0; q < 2; ++q) {
      const int row = h * 64 + q * 32 + (tid >> 3);
      const u16* g = G + (size_t)(b0 + row) * K + k0 + gsw;
      stage16(g, L + (q * 256 + w * 64) * 8, l);
    }
  };

  auto readA = [&](int buf, int mh, short8(&af)[2][2]) {
    const u16* base = &As[buf][0];
#pragma unroll
    for (int i = 0; i < 2; ++i) {
      const int ro = (wr * 64 + mh * 32 + i * 16 + la) * 64;
      af[i][0] = *(const short8*)(base + ro + sx0);
      af[i][1] = *(const short8*)(base + ro + sx1);
    }
  };
  auto readB = [&](int buf, int nh, short8(&bf)[2][2]) {
    const u16* base = &Bs[buf][0];
#pragma unroll
    for (int j = 0; j < 2; ++j) {
      const int ro = (wc * 64 + nh * 32 + j * 16 + la) * 64;
      bf[j][0] = *(const short8*)(base + ro + sx0);
      bf[j][1] = *(const short8*)(base + ro + sx1);
    }
  };
  auto quad = [&](short8(&af)[2][2], short8(&bf)[2][2], int mh, int nh) {
#pragma unroll
    for (int kk = 0; kk < 2; ++kk)
#pragma unroll
      for (int i = 0; i < 2; ++i)
#pragma unroll
        for (int jj = 0; jj < 2; ++jj)
          acc[mh * 2 + i][nh * 2 + jj] =
              MFMA(af[i][kk], bf[jj][kk], acc[mh * 2 + i][nh * 2 + jj]);
  };

  // prologue: B0,A0,B1 half-tiles (12 gll); vmcnt(4) -> A0,B0 landed, B1 in flight.
#pragma unroll
  for (int s = 0; s < 6; ++s) issue(s);
  asm volatile("s_waitcnt vmcnt(4)" ::: "memory");
  __builtin_amdgcn_s_barrier();

  for (int t = 0; t < NT; ++t) {
    const int buf = t & 1;
    short8 af[2][2], af2[2][2], bf0[2][2], bf1[2][2];
    readA(buf, 0, af);   // 4 ds_read_b128
    sched_barrier0();
    readB(buf, 0, bf0);  // 4
    sched_barrier0();
    readB(buf, 1, bf1);  // 4
    sched_barrier0();
    issue(4 * t + 6);    // A.h0(t+1) -> other buffer
    issue(4 * t + 7);    // A.h1(t+1)
    // burst 1: need af+bf0 (first 8 of 12) -> lgkm(4)
    asm volatile("s_waitcnt lgkmcnt(4)" ::: "memory");
    sched_barrier0();
    readA(buf, 1, af2);  // 4 more reads; drain under bursts 1-2
    sched_barrier0();
    __builtin_amdgcn_s_setprio(1);
    quad(af, bf0, 0, 0);
    __builtin_amdgcn_s_setprio(0);
    // burst 2: need bf1 -> outstanding af2 only -> lgkm(4)
    asm volatile("s_waitcnt lgkmcnt(4)" ::: "memory");
    sched_barrier0();
    __builtin_amdgcn_s_setprio(1);
    quad(af, bf1, 0, 1);
    __builtin_amdgcn_s_setprio(0);
    // every wave's B-reads done; sync then overwrite B with t+2
    __builtin_amdgcn_s_barrier();
    issue(4 * t + 8);
    issue(4 * t + 9);
    // burst 3: need af2 -> lgkm(0)
    asm volatile("s_waitcnt lgkmcnt(0)" ::: "memory");
    sched_barrier0();
    __builtin_amdgcn_s_setprio(1);
    quad(af2, bf0, 1, 0);
    quad(af2, bf1, 1, 1);
    __builtin_amdgcn_s_setprio(0);
    // boundary: A(t+1)+B(t+1) complete, B(t+2) (4 gll) stays in flight
    asm volatile("s_waitcnt vmcnt(4)" ::: "memory");
    __builtin_amdgcn_s_barrier();
  }

  // epilogue: C[m0+wr*64+(i>>1)*32+(i&1)*16+qd*4+r][n0+wc*64+(j>>1)*32+(j&1)*16+la]
#pragma unroll
  for (int i = 0; i < 4; ++i)
#pragma unroll
    for (int j = 0; j < 4; ++j) {
      const int r0 = m0 + wr * 64 + (i >> 1) * 32 + (i & 1) * 16 + qd * 4;
      const int c0 = n0 + wc * 64 + (j >> 1) * 32 + (j & 1) * 16 + la;
#pragma unroll
      for (int r = 0; r < 4; ++r) {
        if (of32)
          ((float*)C)[(size_t)(r0 + r) * N + c0] = acc[i][j][r];
        else
          ((u16*)C)[(size_t)(r0 + r) * N + c0] = f2bf(acc[i][j][r]);
      }
    }
}

// ---------- 256x256 counted-lgkm GEMM: A[M,K]*Bt[N,K] -> C[M,N] bf16 ----------
// R3-verified version (92.4 us, 0 bank conflicts).
__global__ __launch_bounds__(512, 2) void gemm256(const u16* __restrict__ A,
                                                  const u16* __restrict__ Bt,
                                                  u16* __restrict__ C,
                                                  int M, int N, int K) {
  __shared__ u16 As[2][256 * 64];  // 64 KiB
  __shared__ u16 Bs[2][256 * 64];  // 64 KiB
  const int tid = threadIdx.x;
  const int w = tid >> 6, l = tid & 63, la = l & 15, qd = l >> 4;
  const int wr = w >> 2, wc = w & 3;

  const int nbx = gridDim.x;
  const int nwg = nbx * gridDim.y;
  int lin = blockIdx.y * nbx + blockIdx.x;
  if ((nwg & 7) == 0) lin = (lin & 7) * (nwg >> 3) + (lin >> 3);
  const int m0 = (lin / nbx) * 256, n0 = (lin % nbx) * 256;
  const int NT = K >> 6;

  const int sx0 = (qd ^ (la & 7)) * 8;        // swizzled 16B-slot (u16 units), kk=0
  const int sx1 = ((4 + qd) ^ (la & 7)) * 8;  // kk=1
  const int gsw = ((tid & 7) ^ ((tid >> 3) & 7)) * 8;  // inverse swizzle, global side

  f32x4 acc[8][4] = {};

  // half-tile stream: s = 4*tile + {0:B.h0, 1:B.h1, 2:A.h0, 3:A.h1}; 2 gll each.
  auto issue = [&](int s) {
    if (s >= NT * 4) return;
    const int kt = s >> 2, part = s & 3, buf = kt & 1;
    const int h = part & 1;
    const u16* G = (part >= 2) ? A : Bt;
    const int b0 = (part >= 2) ? m0 : n0;
    u16* L = ((part >= 2) ? &As[buf][0] : &Bs[buf][0]) + h * 8192;
    const int k0 = kt << 6;
#pragma unroll
    for (int q = 0; q < 2; ++q) {
      const int row = h * 128 + q * 64 + (tid >> 3);
      const u16* g = G + (size_t)(b0 + row) * K + k0 + gsw;
      stage16(g, L + (q * 512 + w * 64) * 8, l);
    }
  };

  auto readA = [&](int buf, int mh, short8(&af)[4][2]) {
    const u16* base = &As[buf][0];
#pragma unroll
    for (int i = 0; i < 4; ++i) {
      const int ro = (wr * 128 + mh * 64 + i * 16 + la) * 64;
      af[i][0] = *(const short8*)(base + ro + sx0);
      af[i][1] = *(const short8*)(base + ro + sx1);
    }
  };
  auto readB = [&](int buf, int nh, short8(&bf)[2][2]) {
    const u16* base = &Bs[buf][0];
#pragma unroll
    for (int j = 0; j < 2; ++j) {
      const int ro = (wc * 64 + nh * 32 + j * 16 + la) * 64;
      bf[j][0] = *(const short8*)(base + ro + sx0);
      bf[j][1] = *(const short8*)(base + ro + sx1);
    }
  };
  auto quad = [&](short8(&af)[4][2], short8(&bf)[2][2], int mh, int nh) {
#pragma unroll
    for (int kk = 0; kk < 2; ++kk)
#pragma unroll
      for (int i = 0; i < 4; ++i)
#pragma unroll
        for (int jj = 0; jj < 2; ++jj)
          acc[mh * 4 + i][nh * 2 + jj] =
              MFMA(af[i][kk], bf[jj][kk], acc[mh * 4 + i][nh * 2 + jj]);
  };

  // prologue: B0.h0,B0.h1,A0.h0,A0.h1,B1.h0,B1.h1 (12 loads); vmcnt(4) ->
  // A0,B0 landed, B1's 4 loads in flight (steady-state invariant).
#pragma unroll
  for (int s = 0; s < 6; ++s) issue(s);
  asm volatile("s_waitcnt vmcnt(4)" ::: "memory");
  __builtin_amdgcn_s_barrier();

  for (int t = 0; t < NT; ++t) {
    const int buf = t & 1;
    short8 af[4][2], af2[4][2], bf0[2][2], bf1[2][2];
    readA(buf, 0, af);   // 8 ds_read_b128
    sched_barrier0();
    readB(buf, 0, bf0);  // 4
    sched_barrier0();
    readB(buf, 1, bf1);  // 4
    sched_barrier0();
    issue(4 * t + 6);
    issue(4 * t + 7);
    asm volatile("s_waitcnt lgkmcnt(4)" ::: "memory");
    sched_barrier0();
    readA(buf, 1, af2);  // 8 more reads; drain under bursts 1-2
    sched_barrier0();
    __builtin_amdgcn_s_setprio(1);
    quad(af, bf0, 0, 0);
    __builtin_amdgcn_s_setprio(0);
    asm volatile("s_waitcnt lgkmcnt(8)" ::: "memory");
    sched_barrier0();
    __builtin_amdgcn_s_setprio(1);
    quad(af, bf1, 0, 1);
    __builtin_amdgcn_s_setprio(0);
    __builtin_amdgcn_s_barrier();
    issue(4 * t + 8);
    issue(4 * t + 9);
    asm volatile("s_waitcnt lgkmcnt(0)" ::: "memory");
    sched_barrier0();
    __builtin_amdgcn_s_setprio(1);
    quad(af2, bf0, 1, 0);
    quad(af2, bf1, 1, 1);
    __builtin_amdgcn_s_setprio(0);
    asm volatile("s_waitcnt vmcnt(4)" ::: "memory");
    __builtin_amdgcn_s_barrier();
  }

  // epilogue: C[m0+wr*128+i*16+qd*4+r][n0+wc*64+j*16+la]
#pragma unroll
  for (int i = 0; i < 8; ++i)
#pragma unroll
    for (int j = 0; j < 4; ++j) {
      const int r0 = m0 + wr * 128 + i * 16 + qd * 4;
      const int c0 = n0 + wc * 64 + j * 16 + la;
#pragma unroll
      for (int r = 0; r < 4; ++r)
        C[(size_t)(r0 + r) * N + c0] = f2bf(acc[i][j][r]);
    }
}

// ---------- RoPE prep ----------
// Q -> Qh row-major [NH][S][96] (bf16, zero-padded).
// K -> Kt TILED: per (head, 64-key tile): [12 slots][64 rows][8 u16].
__global__ __launch_bounds__(256) void rope_prep(const u16* __restrict__ qkv,
                                                 const int* __restrict__ pos,
                                                 u16* __restrict__ Qh,
                                                 u16* __restrict__ Kt) {
  const int s = blockIdx.x;
  const int h = blockIdx.y * 4 + (threadIdx.x >> 6);
  const int t = threadIdx.x & 63;
  const size_t qin = (size_t)s * N3 + h * HD;
  const size_t kin = qin + HID;
  const size_t ob = ((size_t)h * S_LEN + s) * HDP;
  const size_t kb = ((size_t)(h * 32) + (s >> 6)) * 6144 + (size_t)(s & 63) * 8;
  if (t < 32) {
    const float p = (float)pos[s];
    const float inv = exp2f(-(float)t * (13.287712379549449f / 32.0f));
    const float ang = p * inv;
    const float cs = cosf(ang), sn = sinf(ang);
    float x1 = bf2f(qkv[qin + t]), x2 = bf2f(qkv[qin + t + 32]);
    Qh[ob + t] = f2bf(x1 * cs - x2 * sn);
    Qh[ob + t + 32] = f2bf(x2 * cs + x1 * sn);
    x1 = bf2f(qkv[kin + t]);
    x2 = bf2f(qkv[kin + t + 32]);
    Kt[kb + (size_t)(t >> 3) * 512 + (t & 7)] = f2bf(x1 * cs - x2 * sn);
    const int d2 = t + 32;
    Kt[kb + (size_t)(d2 >> 3) * 512 + (d2 & 7)] = f2bf(x2 * cs + x1 * sn);
  } else if (t < 48) {
    const int d = t + 32;  // 64..79 pass-through
    Qh[ob + d] = qkv[qin + d];
    Kt[kb + (size_t)(d >> 3) * 512 + (d & 7)] = qkv[kin + d];
  } else {
    const int d = t + 32;  // 80..95 zero pad
    Qh[ob + d] = 0;
    Kt[kb + (size_t)(d >> 3) * 512 + (d & 7)] = 0;
  }
}

// ---------- Fused causal+ALiBi flash attention ----------
// Grid (16 q-tiles, 32 heads) = 512 blocks; block = ONE q-tile of 128 rows
// (8 waves x 16). Complementary-pair mapping: tile = (h<16) ? p : 15-p, so
// under round-robin placement CU c hosts blocks c and c+256 with tiles x and
// 15-x -> per-CU work = (2x+2)+(2(15-x)+2) = 36 iters, uniform. 2 blocks/CU
// (LDS 45KiB x2, VGPR<=128 via launch_bounds(512,4)): one block's MFMA covers
// the other's barrier/staging stalls (R2 structure had 1 block/CU, no cover).
__global__ __launch_bounds__(512, 4) void attn_fused(const u16* __restrict__ Qh,
                                                     const u16* __restrict__ Kt,
                                                     const u16* __restrict__ Vt,
                                                     u16* __restrict__ AO) {
  __shared__ u16 Ks[2][768 * 8];  // 2 x 12288 B (12 slots x 64 rows x 16 B)
  __shared__ u16 Vs[2][640 * 8];  // 2 x 10240 B (swizzled columns)
  const int tid = threadIdx.x, w = tid >> 6, l = tid & 63;
  const int la = l & 15, qd = l >> 4;
  const int h = blockIdx.y;
  const int p = blockIdx.x;  // 0..15
  const int tile = (h < 16) ? p : 15 - p;
  const int q0 = tile * 128;
  const int nIt = 2 * tile + 2;
  const size_t hS = (size_t)h * S_LEN;

  const int qb = q0 + w * 16;
  const int q = qb + la;
  short8 qf[3];
#pragma unroll
  for (int c = 0; c < 3; ++c)
    qf[c] = *(const short8*)&Qh[(hS + qb + la) * HDP + c * 32 + qd * 8];

  const float slope2 = exp2f(-0.25f * (float)(h + 1)) * LOG2E;
  const float scl2 = QK_SCALE * LOG2E;
  float m_i = -1e30f, l_i = 0.f;
  f32x4 acc[5] = {};

  const u16* gK = Kt + (size_t)h * 32 * 6144;
  const u16* gV = Vt + (size_t)h * HD * S_LEN;

  // Issue (async) staging of key-tile kt_g into buffer buf. K is linear; V is
  // gathered with the inverse column swizzle (read side is conflict-free).
  auto stage = [&](int kt_g, int buf) {
    const u16* gkt = gK + (size_t)kt_g * 6144;
    stage16(gkt + (size_t)(w * 64 + l) * 8, &Ks[buf][(w * 64) * 8], l);
    if (w < 4)
      stage16(gkt + (size_t)(512 + w * 64 + l) * 8, &Ks[buf][(512 + w * 64) * 8], l);
    const u16* gv = gV + (kt_g << 6);
    {
      const int c = w * 64 + l;
      const int row = c >> 3, seg = c & 7;
      const int gcol = ((seg - (row & 7)) & 7) * 8;
      stage16(gv + (size_t)row * S_LEN + gcol, &Vs[buf][(w * 64) * 8], l);
    }
    if (w < 2) {
      const int c = 512 + w * 64 + l;
      const int row = c >> 3, seg = c & 7;
      const int gcol = ((seg - (row & 7)) & 7) * 8;
      stage16(gv + (size_t)row * S_LEN + gcol, &Vs[buf][(512 + w * 64) * 8], l);
    }
  };

  stage(0, 0);
  for (int it = 0; it < nIt; ++it) {
    const int buf = it & 1;
    __syncthreads();  // stage(it) complete; all waves done with buf^1
    if (it + 1 < nIt) stage(it + 1, buf ^ 1);
    const int k0 = it << 6;
    if (k0 >= qb + 16) continue;  // wave-uniform skip of fully-masked tiles

    // --- S^T tiles from LDS (lane-contiguous reads of the tiled K) ---
    f32x4 st[4];
#pragma unroll
    for (int kt = 0; kt < 4; ++kt) {
      short8 kf[3];
#pragma unroll
      for (int c = 0; c < 3; ++c)
        kf[c] = *(const short8*)&Ks[buf][((c * 4 + qd) * 64 + kt * 16 + la) * 8];
      f32x4 z = {};
#pragma unroll
      for (int c = 0; c < 3; ++c) z = MFMA(kf[c], qf[c], z);
      st[kt] = z;
    }

    // --- mask + scale (log2 domain) ---
    const float base = (float)(k0 + qd * 4 - q);  // rel = base + (kt*16 + r)
    float mloc = -1e30f;
    if (k0 + 64 <= qb + 1) {  // tile fully unmasked for every lane of wave
#pragma unroll
      for (int kt = 0; kt < 4; ++kt)
#pragma unroll
        for (int r = 0; r < 4; ++r) {
          const float rel = base + (float)(kt * 16 + r);
          const float v = st[kt][r] * scl2 + slope2 * rel;
          st[kt][r] = v;
          mloc = fmaxf(mloc, v);
        }
    } else {
#pragma unroll
      for (int kt = 0; kt < 4; ++kt)
#pragma unroll
        for (int r = 0; r < 4; ++r) {
          const float rel = base + (float)(kt * 16 + r);
          const float v = (rel <= 0.f) ? st[kt][r] * scl2 + slope2 * rel : -1e30f;
          st[kt][r] = v;
          mloc = fmaxf(mloc, v);
        }
    }
    mloc = fmaxf(mloc, __shfl_xor(mloc, 16));
    mloc = fmaxf(mloc, __shfl_xor(mloc, 32));

    // --- defer-max (T13): rescale only when the max actually grew ---
    if (!__all(mloc - m_i <= 8.0f)) {
      const float nm = fmaxf(m_i, mloc);
      const float al = exp2f(m_i - nm);
      m_i = nm;
      l_i *= al;
#pragma unroll
      for (int dt = 0; dt < 5; ++dt) acc[dt] *= al;
    }

    float ps = 0.f;
    short4v pf[4];
#pragma unroll
    for (int kt = 0; kt < 4; ++kt) {
      short4v pk;
#pragma unroll
      for (int r = 0; r < 4; ++r) {
        const float pv = exp2f(st[kt][r] - m_i);
        ps += pv;
        pk[r] = (short)f2bf(pv);
      }
      pf[kt] = pk;
    }
    ps += __shfl_xor(ps, 16);
    ps += __shfl_xor(ps, 32);
    l_i += ps;

    // --- PV from LDS (swizzled, conflict-free b64): O^T += V^T * P^T ---
    const int cb = qd * 4 + ((la & 7) << 3);
#pragma unroll
    for (int dt = 0; dt < 5; ++dt) {
      const int vrow = (dt * 16 + la) * 64;
#pragma unroll
      for (int kt = 0; kt < 4; ++kt) {
        const short4v vf = *(const short4v*)&Vs[buf][vrow + ((kt * 16 + cb) & 63)];
        acc[dt] = MFMA16(vf, pf[kt], acc[dt]);
      }
    }
  }

  // epilogue: lane holds O^T[d=dt*16+qd*4+r][q]; 8B stores
  const float inv = 1.0f / l_i;
  const size_t row = (size_t)q;
#pragma unroll
  for (int dt = 0; dt < 5; ++dt) {
    us4 o;
#pragma unroll
    for (int r = 0; r < 4; ++r) o[r] = f2bf(acc[dt][r] * inv);
    *(us4*)&AO[row * HID + h * HD + dt * 16 + qd * 4] = o;
  }
}

extern "C" void kernel_launch(void* const* d_in, const int* in_sizes, int n_in,
                              void* d_out, int out_size, void* d_ws, size_t ws_size,
                              hipStream_t stream) {
  const int* pos = (const int*)d_in[0];
  const void* hidden = d_in[1];
  const void* w_qkv = d_in[2];
  const void* w_out = d_in[3];
  u16* ws = (u16*)d_ws;

  // ws layout (u16 elements). Hb dead after GEMM1 -> Vt aliases it (same size).
  // WtQ dead after GEMM1 -> Qh/Kh/AO alias into it (17.8M <= 19.66M).
  u16* Hb = ws;                                  //  5,242,880
  u16* WtQ = Hb + (size_t)S_LEN * HID;           // 19,660,800
  u16* WtO = WtQ + (size_t)N3 * HID;             //  6,553,600
  u16* qkv = WtO + (size_t)HID * HID;            // 15,728,640
  int* flag = (int*)(qkv + (size_t)S_LEN * N3);  // 1 int
  u16* Vt = Hb;                                  //  5,242,880 (alias)
  u16* Qh = WtQ;                                 //  6,291,456 (alias)
  u16* Kh = Qh + (size_t)NHEAD * S_LEN * HDP;    //  6,291,456 (alias, tiled layout)
  u16* AO = Kh + (size_t)NHEAD * S_LEN * HDP;    //  5,242,880 (alias)

  detect_dtype<<<1, 256, 0, stream>>>((const u32*)hidden, flag);
  convert_hidden<<<(S_LEN * HID / 4 + 255) / 256, 256, 0, stream>>>(hidden, Hb,
                                                                    S_LEN * HID / 4, flag);
  // w_qkv [HID][N3] -> WtQ [N3][HID]
  transpose64<<<dim3(N3 / 64, HID / 64), 256, 0, stream>>>(w_qkv, WtQ, N3, 0, HID, flag);
  // w_out [HID][HID] -> WtO [HID][HID]
  transpose64<<<dim3(HID / 64, HID / 64), 256, 0, stream>>>(w_out, WtO, HID, 0, HID, flag);
  gemm256<<<dim3(N3 / 256, S_LEN / 256), 512, 0, stream>>>(Hb, WtQ, qkv, S_LEN, N3, HID);
  // qkv[s][2*HID + c] -> Vt[c][s]
  transpose64<<<dim3(HID / 64, S_LEN / 64), 256, 0, stream>>>(qkv, Vt, N3, 2 * HID, S_LEN,
                                                              nullptr);
  rope_prep<<<dim3(S_LEN, NHEAD / 4), 256, 0, stream>>>(qkv, pos, Qh, Kh);
  attn_fused<<<dim3(16, NHEAD), 512, 0, stream>>>(Qh, Kh, Vt, AO);
  gemm128c<<<dim3(HID / 128, S_LEN / 128), 256, 0, stream>>>(AO, WtO, d_out, S_LEN, HID,
                                                             HID, flag);
}

// Round 7
// 372.767 us; speedup vs baseline: 1.2020x; 1.0447x over previous
//
#include <hip/hip_runtime.h>
#include <type_traits>
#include <utility>

typedef unsigned short u16;
typedef unsigned int u32;
typedef __attribute__((ext_vector_type(8))) short short8;
typedef __attribute__((ext_vector_type(8))) __bf16 bhalf8;
typedef __attribute__((ext_vector_type(4))) short short4v;
typedef __attribute__((ext_vector_type(4))) __bf16 bhalf4;
typedef __attribute__((ext_vector_type(4))) float f32x4;
typedef __attribute__((ext_vector_type(4))) unsigned short us4;

#define S_LEN 2048
#define NHEAD 32
#define HD 80
#define HDP 96
#define HID 2560
#define N3 7680
#define QK_SCALE 0.11180339887498949f  // 80^-0.5
#define LOG2E 1.4426950408889634f

// ---------- MFMA K=32 wrapper (hedge: builtin may take __bf16x8 or shortx8) ----------
template <typename T, typename = void> struct MfmaTakes : std::false_type {};
template <typename T>
struct MfmaTakes<T, std::void_t<decltype(__builtin_amdgcn_mfma_f32_16x16x32_bf16(
                       std::declval<T>(), std::declval<T>(), std::declval<f32x4>(), 0, 0, 0))>>
    : std::true_type {};

template <typename AB>
__device__ inline f32x4 mfma_raw(AB a, AB b, f32x4 c) {
  return __builtin_amdgcn_mfma_f32_16x16x32_bf16(a, b, c, 0, 0, 0);
}
using mfma_ab_t = std::conditional_t<MfmaTakes<bhalf8>::value, bhalf8, short8>;
__device__ inline f32x4 MFMA(short8 a, short8 b, f32x4 c) {
  return mfma_raw<mfma_ab_t>(__builtin_bit_cast(mfma_ab_t, a),
                             __builtin_bit_cast(mfma_ab_t, b), c);
}

// ---------- MFMA K=16 wrapper (16x16x16 bf16), with emulation fallback ----------
#if defined(__has_builtin)
#if __has_builtin(__builtin_amdgcn_mfma_f32_16x16x16bf16_1k)
#define MFMA16_RAW(a, b, c) __builtin_amdgcn_mfma_f32_16x16x16bf16_1k(a, b, c, 0, 0, 0)
#define HAVE_MFMA16 1
#elif __has_builtin(__builtin_amdgcn_mfma_f32_16x16x16_bf16)
#define MFMA16_RAW(a, b, c) __builtin_amdgcn_mfma_f32_16x16x16_bf16(a, b, c, 0, 0, 0)
#define HAVE_MFMA16 1
#endif
#endif

#ifdef HAVE_MFMA16
template <typename T, typename = void> struct M16Takes : std::false_type {};
template <typename T>
struct M16Takes<T, std::void_t<decltype(MFMA16_RAW(std::declval<T>(), std::declval<T>(),
                                                   std::declval<f32x4>()))>> : std::true_type {};
using m16_t = std::conditional_t<M16Takes<bhalf4>::value, bhalf4, short4v>;
__device__ inline f32x4 MFMA16(short4v a, short4v b, f32x4 c) {
  return MFMA16_RAW(__builtin_bit_cast(m16_t, a), __builtin_bit_cast(m16_t, b), c);
}
#else
// Emulate K=16 via K=32 MFMA with zero upper k-half in BOTH operands.
__device__ inline f32x4 MFMA16(short4v a, short4v b, f32x4 c) {
  short8 a8 = {a[0], a[1], a[2], a[3], 0, 0, 0, 0};
  short8 b8 = {b[0], b[1], b[2], b[3], 0, 0, 0, 0};
  return MFMA(a8, b8, c);
}
#endif

__device__ inline float bf2f(u16 b) { return __uint_as_float(((u32)b) << 16); }
__device__ inline u16 f2bf(float f) {
  u32 u = __float_as_uint(f);
  u += 0x7fffu + ((u >> 16) & 1u);  // round-to-nearest-even
  return (u16)(u >> 16);
}

typedef __attribute__((address_space(1))) void as1_void;
typedef __attribute__((address_space(3))) void as3_void;

#if defined(__has_builtin)
#if __has_builtin(__builtin_amdgcn_global_load_lds)
#define HAVE_GLL 1
#endif
#endif

// Stage 16B/lane: global (per-lane addr) -> LDS (wave-uniform base + lane*16).
__device__ inline void stage16(const u16* g, u16* lds_base, int lane) {
#ifdef HAVE_GLL
  (void)lane;
  __builtin_amdgcn_global_load_lds((as1_void*)g, (as3_void*)lds_base, 16, 0, 0);
#else
  *(short8*)(lds_base + lane * 8) = *(const short8*)g;
#endif
}

__device__ inline void sched_barrier0() {
#if defined(__has_builtin)
#if __has_builtin(__builtin_amdgcn_sched_barrier)
  __builtin_amdgcn_sched_barrier(0);
#endif
#endif
}

// ---------- dtype detection: are the float tensors f32 or bf16 on device? ----------
__global__ __launch_bounds__(256) void detect_dtype(const u32* __restrict__ words,
                                                    int* __restrict__ flag) {
  __shared__ int red[256];
  int junk = 0;
  for (int i = threadIdx.x; i < 2048; i += 256) {
    u16 lo = (u16)(words[i] & 0xffffu);
    u32 e = (lo >> 7) & 0xffu;  // bf16 exponent field
    junk += (e >= 137u);        // |x| >= 1024, or NaN/Inf
  }
  red[threadIdx.x] = junk;
  __syncthreads();
  for (int s = 128; s > 0; s >>= 1) {
    if (threadIdx.x < s) red[threadIdx.x] += red[threadIdx.x + s];
    __syncthreads();
  }
  if (threadIdx.x == 0) flag[0] = (red[0] > 64) ? 1 : 0;  // 1 = f32, 0 = bf16
}

// ---------- hidden_states -> bf16 (contiguous) ----------
__global__ __launch_bounds__(256) void convert_hidden(const void* __restrict__ in,
                                                      u16* __restrict__ out, int n4,
                                                      const int* __restrict__ flagp) {
  const int f = *flagp;
  int i = blockIdx.x * 256 + threadIdx.x;
  if (i >= n4) return;
  if (f) {
    const float* inf = (const float*)in;
    us4 o;
#pragma unroll
    for (int j = 0; j < 4; ++j) o[j] = f2bf(inf[(size_t)i * 4 + j]);
    *(us4*)&out[(size_t)i * 4] = o;
  } else {
    *(us4*)&out[(size_t)i * 4] = *(const us4*)&((const u16*)in)[(size_t)i * 4];
  }
}

// ---------- vectorized 64x64 transpose (+optional f32->bf16 convert) ----------
__global__ __launch_bounds__(256) void transpose64(const void* __restrict__ in,
                                                   u16* __restrict__ out,
                                                   int istride, int ioff, int ostride,
                                                   const int* __restrict__ flagp) {
  __shared__ u16 tile[64][66];
  const int f = flagp ? *flagp : 0;
  const int bx = blockIdx.x * 64, by = blockIdx.y * 64;
  const int tx4 = (threadIdx.x & 15) * 4, ty = threadIdx.x >> 4;  // ty 0..15
#pragma unroll
  for (int i = 0; i < 4; ++i) {
    const int row = ty + i * 16;
    const size_t idx = (size_t)(by + row) * istride + ioff + bx + tx4;
    us4 v;
    if (f) {
      const f32x4 x = *(const f32x4*)&((const float*)in)[idx];
#pragma unroll
      for (int j = 0; j < 4; ++j) v[j] = f2bf(x[j]);
    } else {
      v = *(const us4*)&((const u16*)in)[idx];
    }
    *(u32*)&tile[row][tx4] = (u32)v[0] | ((u32)v[1] << 16);
    *(u32*)&tile[row][tx4 + 2] = (u32)v[2] | ((u32)v[3] << 16);
  }
  __syncthreads();
#pragma unroll
  for (int i = 0; i < 4; ++i) {
    const int oc = ty + i * 16;
    us4 o;
#pragma unroll
    for (int j = 0; j < 4; ++j) o[j] = tile[tx4 + j][oc];
    *(us4*)&out[(size_t)(bx + oc) * ostride + by + tx4] = o;
  }
}

// ---------- 128x128 counted-lgkm GEMM (output GEMM), 3-buffer B / 1 barrier ----------
// Same schedule as gemm256 below, scaled to 128^2: 4 waves (2Mx2N, 64x64/wave),
// BK=64, LDS 2x16K(A)+3x16K(B)=80KiB -> 2 blocks/CU, grid 320 blocks.
__global__ __launch_bounds__(256, 2) void gemm128c(const u16* __restrict__ A,
                                                   const u16* __restrict__ Bt,
                                                   void* __restrict__ C,
                                                   int M, int N, int K,
                                                   const int* __restrict__ flagp) {
  __shared__ u16 As[2][128 * 64];  // 2 x 16 KiB
  __shared__ u16 Bs[3][128 * 64];  // 3 x 16 KiB
  const int tid = threadIdx.x;
  const int w = tid >> 6, l = tid & 63, la = l & 15, qd = l >> 4;
  const int wr = w >> 1, wc = w & 1;
  const int of32 = flagp ? *flagp : 0;

  const int nbx = gridDim.x;
  const int nwg = nbx * gridDim.y;
  int lin = blockIdx.y * nbx + blockIdx.x;
  if ((nwg & 7) == 0) lin = (lin & 7) * (nwg >> 3) + (lin >> 3);
  const int m0 = (lin / nbx) * 128, n0 = (lin % nbx) * 128;
  const int NT = K >> 6;

  const int sx0 = (qd ^ (la & 7)) * 8;        // swizzled 16B-slot, kk=0
  const int sx1 = ((4 + qd) ^ (la & 7)) * 8;  // kk=1
  const int gsw = ((tid & 7) ^ ((tid >> 3) & 7)) * 8;  // inverse swizzle, global side

  f32x4 acc[4][4] = {};

  // half-tile stream: s = 4*tile + {0:B.h0, 1:B.h1, 2:A.h0, 3:A.h1}; 2 gll each.
  auto issue = [&](int s) {
    if (s >= NT * 4) return;
    const int kt = s >> 2, part = s & 3;
    const int h = part & 1;
    const u16* G = (part >= 2) ? A : Bt;
    const int b0 = (part >= 2) ? m0 : n0;
    u16* L = ((part >= 2) ? &As[kt & 1][0] : &Bs[kt % 3][0]) + h * 4096;
    const int k0 = kt << 6;
#pragma unroll
    for (int q = 0; q < 2; ++q) {
      const int row = h * 64 + q * 32 + (tid >> 3);
      const u16* g = G + (size_t)(b0 + row) * K + k0 + gsw;
      stage16(g, L + (q * 256 + w * 64) * 8, l);
    }
  };

  auto readA = [&](int buf, int mh, short8(&af)[2][2]) {
    const u16* base = &As[buf][0];
#pragma unroll
    for (int i = 0; i < 2; ++i) {
      const int ro = (wr * 64 + mh * 32 + i * 16 + la) * 64;
      af[i][0] = *(const short8*)(base + ro + sx0);
      af[i][1] = *(const short8*)(base + ro + sx1);
    }
  };
  auto readB = [&](int buf, int nh, short8(&bf)[2][2]) {
    const u16* base = &Bs[buf][0];
#pragma unroll
    for (int j = 0; j < 2; ++j) {
      const int ro = (wc * 64 + nh * 32 + j * 16 + la) * 64;
      bf[j][0] = *(const short8*)(base + ro + sx0);
      bf[j][1] = *(const short8*)(base + ro + sx1);
    }
  };
  auto quad = [&](short8(&af)[2][2], short8(&bf)[2][2], int mh, int nh) {
#pragma unroll
    for (int kk = 0; kk < 2; ++kk)
#pragma unroll
      for (int i = 0; i < 2; ++i)
#pragma unroll
        for (int jj = 0; jj < 2; ++jj)
          acc[mh * 2 + i][nh * 2 + jj] =
              MFMA(af[i][kk], bf[jj][kk], acc[mh * 2 + i][nh * 2 + jj]);
  };

  // prologue: B0.h0,B0.h1,A0.h0,A0.h1,B1.h0,B1.h1; vmcnt(4) -> A0,B0 landed.
#pragma unroll
  for (int s = 0; s < 6; ++s) issue(s);
  asm volatile("s_waitcnt vmcnt(4)" ::: "memory");
  __builtin_amdgcn_s_barrier();

  for (int t = 0; t < NT; ++t) {
    const int ab = t & 1, bb = t % 3;
    short8 af[2][2], af2[2][2], bf0[2][2], bf1[2][2];
    readA(ab, 0, af);   // 4 ds_read_b128
    sched_barrier0();
    readB(bb, 0, bf0);  // 4
    sched_barrier0();
    readB(bb, 1, bf1);  // 4
    sched_barrier0();
    // A(t+1): writes As[(t+1)&1], read in t-1, drained by t-1's lgkm(0)+barrier.
    issue(4 * t + 6);
    issue(4 * t + 7);
    // B(t+2): writes Bs[(t+2)%3], read in t-1, drained likewise -> issue at TOP.
    issue(4 * t + 8);
    issue(4 * t + 9);
    // burst 1: need af+bf0 (first 8 of 12) -> lgkm(4)
    asm volatile("s_waitcnt lgkmcnt(4)" ::: "memory");
    sched_barrier0();
    readA(ab, 1, af2);  // 4 more reads; drain under bursts 1-2
    sched_barrier0();
    __builtin_amdgcn_s_setprio(1);
    quad(af, bf0, 0, 0);
    __builtin_amdgcn_s_setprio(0);
    // burst 2: need bf1 -> outstanding af2 only -> lgkm(4)
    asm volatile("s_waitcnt lgkmcnt(4)" ::: "memory");
    sched_barrier0();
    __builtin_amdgcn_s_setprio(1);
    quad(af, bf1, 0, 1);
    __builtin_amdgcn_s_setprio(0);
    // burst 3: need af2 -> lgkm(0)
    asm volatile("s_waitcnt lgkmcnt(0)" ::: "memory");
    sched_barrier0();
    __builtin_amdgcn_s_setprio(1);
    quad(af2, bf0, 1, 0);
    quad(af2, bf1, 1, 1);
    __builtin_amdgcn_s_setprio(0);
    // boundary: vmcnt(4) keeps only B(t+2) (newest 4, FIFO) in flight
    // => A(t+1), B(t+1) landed. ONE barrier per tile.
    asm volatile("s_waitcnt vmcnt(4)" ::: "memory");
    __builtin_amdgcn_s_barrier();
  }

  // epilogue
#pragma unroll
  for (int i = 0; i < 4; ++i)
#pragma unroll
    for (int j = 0; j < 4; ++j) {
      const int r0 = m0 + wr * 64 + (i >> 1) * 32 + (i & 1) * 16 + qd * 4;
      const int c0 = n0 + wc * 64 + (j >> 1) * 32 + (j & 1) * 16 + la;
#pragma unroll
      for (int r = 0; r < 4; ++r) {
        if (of32)
          ((float*)C)[(size_t)(r0 + r) * N + c0] = acc[i][j][r];
        else
          ((u16*)C)[(size_t)(r0 + r) * N + c0] = f2bf(acc[i][j][r]);
      }
    }
}

// ---------- 256x256 counted-lgkm GEMM, 3-buffer B / 1 barrier per tile ----------
// Evolution of the R3-verified schedule: Bs triple-buffered (kt%3) so B(t+2)
// issues at tile TOP (writes a buffer drained in t-1) -> the mid-tile barrier
// is deleted (40 fewer barriers) and B prefetch lead grows ~2 tiles.
// LDS = 2x32K(A) + 3x32K(B) = 160 KiB (full CU pool, 1 block/CU as before).
__global__ __launch_bounds__(512, 2) void gemm256(const u16* __restrict__ A,
                                                  const u16* __restrict__ Bt,
                                                  u16* __restrict__ C,
                                                  int M, int N, int K) {
  __shared__ u16 As[2][256 * 64];  // 64 KiB
  __shared__ u16 Bs[3][256 * 64];  // 96 KiB
  const int tid = threadIdx.x;
  const int w = tid >> 6, l = tid & 63, la = l & 15, qd = l >> 4;
  const int wr = w >> 2, wc = w & 3;

  const int nbx = gridDim.x;
  const int nwg = nbx * gridDim.y;
  int lin = blockIdx.y * nbx + blockIdx.x;
  if ((nwg & 7) == 0) lin = (lin & 7) * (nwg >> 3) + (lin >> 3);
  const int m0 = (lin / nbx) * 256, n0 = (lin % nbx) * 256;
  const int NT = K >> 6;

  const int sx0 = (qd ^ (la & 7)) * 8;        // swizzled 16B-slot (u16 units), kk=0
  const int sx1 = ((4 + qd) ^ (la & 7)) * 8;  // kk=1
  const int gsw = ((tid & 7) ^ ((tid >> 3) & 7)) * 8;  // inverse swizzle, global side

  f32x4 acc[8][4] = {};

  // half-tile stream: s = 4*tile + {0:B.h0, 1:B.h1, 2:A.h0, 3:A.h1}; 2 gll each.
  auto issue = [&](int s) {
    if (s >= NT * 4) return;
    const int kt = s >> 2, part = s & 3;
    const int h = part & 1;
    const u16* G = (part >= 2) ? A : Bt;
    const int b0 = (part >= 2) ? m0 : n0;
    u16* L = ((part >= 2) ? &As[kt & 1][0] : &Bs[kt % 3][0]) + h * 8192;
    const int k0 = kt << 6;
#pragma unroll
    for (int q = 0; q < 2; ++q) {
      const int row = h * 128 + q * 64 + (tid >> 3);
      const u16* g = G + (size_t)(b0 + row) * K + k0 + gsw;
      stage16(g, L + (q * 512 + w * 64) * 8, l);
    }
  };

  auto readA = [&](int buf, int mh, short8(&af)[4][2]) {
    const u16* base = &As[buf][0];
#pragma unroll
    for (int i = 0; i < 4; ++i) {
      const int ro = (wr * 128 + mh * 64 + i * 16 + la) * 64;
      af[i][0] = *(const short8*)(base + ro + sx0);
      af[i][1] = *(const short8*)(base + ro + sx1);
    }
  };
  auto readB = [&](int buf, int nh, short8(&bf)[2][2]) {
    const u16* base = &Bs[buf][0];
#pragma unroll
    for (int j = 0; j < 2; ++j) {
      const int ro = (wc * 64 + nh * 32 + j * 16 + la) * 64;
      bf[j][0] = *(const short8*)(base + ro + sx0);
      bf[j][1] = *(const short8*)(base + ro + sx1);
    }
  };
  auto quad = [&](short8(&af)[4][2], short8(&bf)[2][2], int mh, int nh) {
#pragma unroll
    for (int kk = 0; kk < 2; ++kk)
#pragma unroll
      for (int i = 0; i < 4; ++i)
#pragma unroll
        for (int jj = 0; jj < 2; ++jj)
          acc[mh * 4 + i][nh * 2 + jj] =
              MFMA(af[i][kk], bf[jj][kk], acc[mh * 4 + i][nh * 2 + jj]);
  };

  // prologue: B0.h0,B0.h1,A0.h0,A0.h1,B1.h0,B1.h1 (12 loads); vmcnt(4) ->
  // A0,B0 landed, B1's 4 loads in flight (steady-state invariant).
#pragma unroll
  for (int s = 0; s < 6; ++s) issue(s);
  asm volatile("s_waitcnt vmcnt(4)" ::: "memory");
  __builtin_amdgcn_s_barrier();

  for (int t = 0; t < NT; ++t) {
    const int ab = t & 1, bb = t % 3;
    short8 af[4][2], af2[4][2], bf0[2][2], bf1[2][2];
    // ---- issue all fragment reads for this tile (order pinned) ----
    readA(ab, 0, af);   // 8 ds_read_b128
    sched_barrier0();
    readB(bb, 0, bf0);  // 4
    sched_barrier0();
    readB(bb, 1, bf1);  // 4
    sched_barrier0();
    // A(t+1) -> As[(t+1)&1]: read in t-1, drained by t-1's lgkm(0)+barrier.
    issue(4 * t + 6);
    issue(4 * t + 7);
    // B(t+2) -> Bs[(t+2)%3]: read in t-1, drained likewise -> issue at TOP
    // (this is what deletes the mid-tile barrier).
    issue(4 * t + 8);
    issue(4 * t + 9);
    // ---- burst 1: need af+bf0 (first 12 of 16) -> lgkm(4) ----
    asm volatile("s_waitcnt lgkmcnt(4)" ::: "memory");
    sched_barrier0();
    readA(ab, 1, af2);  // 8 more reads; drain under bursts 1-2
    sched_barrier0();
    __builtin_amdgcn_s_setprio(1);
    quad(af, bf0, 0, 0);
    __builtin_amdgcn_s_setprio(0);
    // ---- burst 2: need bf1 (outstanding <= bf1(4)+af2(8)) -> lgkm(8) ----
    asm volatile("s_waitcnt lgkmcnt(8)" ::: "memory");
    sched_barrier0();
    __builtin_amdgcn_s_setprio(1);
    quad(af, bf1, 0, 1);
    __builtin_amdgcn_s_setprio(0);
    // ---- burst 3: need af2 -> lgkm(0) ----
    asm volatile("s_waitcnt lgkmcnt(0)" ::: "memory");
    sched_barrier0();
    __builtin_amdgcn_s_setprio(1);
    quad(af2, bf0, 1, 0);
    quad(af2, bf1, 1, 1);
    __builtin_amdgcn_s_setprio(0);
    // ---- boundary: vmcnt(4) keeps only B(t+2) (newest 4, FIFO) in flight
    // => A(t+1), B(t+1) landed. ONE barrier per tile. ----
    asm volatile("s_waitcnt vmcnt(4)" ::: "memory");
    __builtin_amdgcn_s_barrier();
  }

  // epilogue: C[m0+wr*128+i*16+qd*4+r][n0+wc*64+j*16+la]
#pragma unroll
  for (int i = 0; i < 8; ++i)
#pragma unroll
    for (int j = 0; j < 4; ++j) {
      const int r0 = m0 + wr * 128 + i * 16 + qd * 4;
      const int c0 = n0 + wc * 64 + j * 16 + la;
#pragma unroll
      for (int r = 0; r < 4; ++r)
        C[(size_t)(r0 + r) * N + c0] = f2bf(acc[i][j][r]);
    }
}

// ---------- RoPE prep ----------
// Q -> Qh row-major [NH][S][96] (bf16, zero-padded).
// K -> Kt TILED: per (head, 64-key tile): [12 slots][64 rows][8 u16].
__global__ __launch_bounds__(256) void rope_prep(const u16* __restrict__ qkv,
                                                 const int* __restrict__ pos,
                                                 u16* __restrict__ Qh,
                                                 u16* __restrict__ Kt) {
  const int s = blockIdx.x;
  const int h = blockIdx.y * 4 + (threadIdx.x >> 6);
  const int t = threadIdx.x & 63;
  const size_t qin = (size_t)s * N3 + h * HD;
  const size_t kin = qin + HID;
  const size_t ob = ((size_t)h * S_LEN + s) * HDP;
  const size_t kb = ((size_t)(h * 32) + (s >> 6)) * 6144 + (size_t)(s & 63) * 8;
  if (t < 32) {
    const float p = (float)pos[s];
    const float inv = exp2f(-(float)t * (13.287712379549449f / 32.0f));
    const float ang = p * inv;
    const float cs = cosf(ang), sn = sinf(ang);
    float x1 = bf2f(qkv[qin + t]), x2 = bf2f(qkv[qin + t + 32]);
    Qh[ob + t] = f2bf(x1 * cs - x2 * sn);
    Qh[ob + t + 32] = f2bf(x2 * cs + x1 * sn);
    x1 = bf2f(qkv[kin + t]);
    x2 = bf2f(qkv[kin + t + 32]);
    Kt[kb + (size_t)(t >> 3) * 512 + (t & 7)] = f2bf(x1 * cs - x2 * sn);
    const int d2 = t + 32;
    Kt[kb + (size_t)(d2 >> 3) * 512 + (d2 & 7)] = f2bf(x2 * cs + x1 * sn);
  } else if (t < 48) {
    const int d = t + 32;  // 64..79 pass-through
    Qh[ob + d] = qkv[qin + d];
    Kt[kb + (size_t)(d >> 3) * 512 + (d & 7)] = qkv[kin + d];
  } else {
    const int d = t + 32;  // 80..95 zero pad
    Qh[ob + d] = 0;
    Kt[kb + (size_t)(d >> 3) * 512 + (d & 7)] = 0;
  }
}

// ---------- Fused causal+ALiBi flash attention ----------
// Grid (16 q-tiles, 32 heads) = 512 blocks; block = ONE q-tile of 128 rows
// (8 waves x 16). Complementary-pair mapping: tile = (h<16) ? p : 15-p ->
// CU c hosts tiles x and 15-x -> uniform 36 iters/CU; 2 blocks/CU overlap.
__global__ __launch_bounds__(512, 4) void attn_fused(const u16* __restrict__ Qh,
                                                     const u16* __restrict__ Kt,
                                                     const u16* __restrict__ Vt,
                                                     u16* __restrict__ AO) {
  __shared__ u16 Ks[2][768 * 8];  // 2 x 12288 B (12 slots x 64 rows x 16 B)
  __shared__ u16 Vs[2][640 * 8];  // 2 x 10240 B (swizzled columns)
  const int tid = threadIdx.x, w = tid >> 6, l = tid & 63;
  const int la = l & 15, qd = l >> 4;
  const int h = blockIdx.y;
  const int p = blockIdx.x;  // 0..15
  const int tile = (h < 16) ? p : 15 - p;
  const int q0 = tile * 128;
  const int nIt = 2 * tile + 2;
  const size_t hS = (size_t)h * S_LEN;

  const int qb = q0 + w * 16;
  const int q = qb + la;
  short8 qf[3];
#pragma unroll
  for (int c = 0; c < 3; ++c)
    qf[c] = *(const short8*)&Qh[(hS + qb + la) * HDP + c * 32 + qd * 8];

  const float slope2 = exp2f(-0.25f * (float)(h + 1)) * LOG2E;
  const float scl2 = QK_SCALE * LOG2E;
  float m_i = -1e30f, l_i = 0.f;
  f32x4 acc[5] = {};

  const u16* gK = Kt + (size_t)h * 32 * 6144;
  const u16* gV = Vt + (size_t)h * HD * S_LEN;

  auto stage = [&](int kt_g, int buf) {
    const u16* gkt = gK + (size_t)kt_g * 6144;
    stage16(gkt + (size_t)(w * 64 + l) * 8, &Ks[buf][(w * 64) * 8], l);
    if (w < 4)
      stage16(gkt + (size_t)(512 + w * 64 + l) * 8, &Ks[buf][(512 + w * 64) * 8], l);
    const u16* gv = gV + (kt_g << 6);
    {
      const int c = w * 64 + l;
      const int row = c >> 3, seg = c & 7;
      const int gcol = ((seg - (row & 7)) & 7) * 8;
      stage16(gv + (size_t)row * S_LEN + gcol, &Vs[buf][(w * 64) * 8], l);
    }
    if (w < 2) {
      const int c = 512 + w * 64 + l;
      const int row = c >> 3, seg = c & 7;
      const int gcol = ((seg - (row & 7)) & 7) * 8;
      stage16(gv + (size_t)row * S_LEN + gcol, &Vs[buf][(512 + w * 64) * 8], l);
    }
  };

  stage(0, 0);
  for (int it = 0; it < nIt; ++it) {
    const int buf = it & 1;
    __syncthreads();  // stage(it) complete; all waves done with buf^1
    if (it + 1 < nIt) stage(it + 1, buf ^ 1);
    const int k0 = it << 6;
    if (k0 >= qb + 16) continue;  // wave-uniform skip of fully-masked tiles

    // --- S^T tiles from LDS (lane-contiguous reads of the tiled K) ---
    f32x4 st[4];
#pragma unroll
    for (int kt = 0; kt < 4; ++kt) {
      short8 kf[3];
#pragma unroll
      for (int c = 0; c < 3; ++c)
        kf[c] = *(const short8*)&Ks[buf][((c * 4 + qd) * 64 + kt * 16 + la) * 8];
      f32x4 z = {};
#pragma unroll
      for (int c = 0; c < 3; ++c) z = MFMA(kf[c], qf[c], z);
      st[kt] = z;
    }

    // --- mask + scale (log2 domain) ---
    const float base = (float)(k0 + qd * 4 - q);  // rel = base + (kt*16 + r)
    float mloc = -1e30f;
    if (k0 + 64 <= qb + 1) {  // tile fully unmasked for every lane of wave
#pragma unroll
      for (int kt = 0; kt < 4; ++kt)
#pragma unroll
        for (int r = 0; r < 4; ++r) {
          const float rel = base + (float)(kt * 16 + r);
          const float v = st[kt][r] * scl2 + slope2 * rel;
          st[kt][r] = v;
          mloc = fmaxf(mloc, v);
        }
    } else {
#pragma unroll
      for (int kt = 0; kt < 4; ++kt)
#pragma unroll
        for (int r = 0; r < 4; ++r) {
          const float rel = base + (float)(kt * 16 + r);
          const float v = (rel <= 0.f) ? st[kt][r] * scl2 + slope2 * rel : -1e30f;
          st[kt][r] = v;
          mloc = fmaxf(mloc, v);
        }
    }
    mloc = fmaxf(mloc, __shfl_xor(mloc, 16));
    mloc = fmaxf(mloc, __shfl_xor(mloc, 32));

    // --- defer-max (T13): rescale only when the max actually grew ---
    if (!__all(mloc - m_i <= 8.0f)) {
      const float nm = fmaxf(m_i, mloc);
      const float al = exp2f(m_i - nm);
      m_i = nm;
      l_i *= al;
#pragma unroll
      for (int dt = 0; dt < 5; ++dt) acc[dt] *= al;
    }

    float ps = 0.f;
    short4v pf[4];
#pragma unroll
    for (int kt = 0; kt < 4; ++kt) {
      short4v pk;
#pragma unroll
      for (int r = 0; r < 4; ++r) {
        const float pv = exp2f(st[kt][r] - m_i);
        ps += pv;
        pk[r] = (short)f2bf(pv);
      }
      pf[kt] = pk;
    }
    ps += __shfl_xor(ps, 16);
    ps += __shfl_xor(ps, 32);
    l_i += ps;

    // --- PV from LDS (swizzled, conflict-free b64): O^T += V^T * P^T ---
    const int cb = qd * 4 + ((la & 7) << 3);
#pragma unroll
    for (int dt = 0; dt < 5; ++dt) {
      const int vrow = (dt * 16 + la) * 64;
#pragma unroll
      for (int kt = 0; kt < 4; ++kt) {
        const short4v vf = *(const short4v*)&Vs[buf][vrow + ((kt * 16 + cb) & 63)];
        acc[dt] = MFMA16(vf, pf[kt], acc[dt]);
      }
    }
  }

  // epilogue: lane holds O^T[d=dt*16+qd*4+r][q]; 8B stores
  const float inv = 1.0f / l_i;
  const size_t row = (size_t)q;
#pragma unroll
  for (int dt = 0; dt < 5; ++dt) {
    us4 o;
#pragma unroll
    for (int r = 0; r < 4; ++r) o[r] = f2bf(acc[dt][r] * inv);
    *(us4*)&AO[row * HID + h * HD + dt * 16 + qd * 4] = o;
  }
}

extern "C" void kernel_launch(void* const* d_in, const int* in_sizes, int n_in,
                              void* d_out, int out_size, void* d_ws, size_t ws_size,
                              hipStream_t stream) {
  const int* pos = (const int*)d_in[0];
  const void* hidden = d_in[1];
  const void* w_qkv = d_in[2];
  const void* w_out = d_in[3];
  u16* ws = (u16*)d_ws;

  // ws layout (u16 elements). Hb dead after GEMM1 -> Vt aliases it (same size).
  // WtQ dead after GEMM1 -> Qh/Kh/AO alias into it (17.8M <= 19.66M).
  u16* Hb = ws;                                  //  5,242,880
  u16* WtQ = Hb + (size_t)S_LEN * HID;           // 19,660,800
  u16* WtO = WtQ + (size_t)N3 * HID;             //  6,553,600
  u16* qkv = WtO + (size_t)HID * HID;            // 15,728,640
  int* flag = (int*)(qkv + (size_t)S_LEN * N3);  // 1 int
  u16* Vt = Hb;                                  //  5,242,880 (alias)
  u16* Qh = WtQ;                                 //  6,291,456 (alias)
  u16* Kh = Qh + (size_t)NHEAD * S_LEN * HDP;    //  6,291,456 (alias, tiled layout)
  u16* AO = Kh + (size_t)NHEAD * S_LEN * HDP;    //  5,242,880 (alias)

  detect_dtype<<<1, 256, 0, stream>>>((const u32*)hidden, flag);
  convert_hidden<<<(S_LEN * HID / 4 + 255) / 256, 256, 0, stream>>>(hidden, Hb,
                                                                    S_LEN * HID / 4, flag);
  // w_qkv [HID][N3] -> WtQ [N3][HID]
  transpose64<<<dim3(N3 / 64, HID / 64), 256, 0, stream>>>(w_qkv, WtQ, N3, 0, HID, flag);
  // w_out [HID][HID] -> WtO [HID][HID]
  transpose64<<<dim3(HID / 64, HID / 64), 256, 0, stream>>>(w_out, WtO, HID, 0, HID, flag);
  gemm256<<<dim3(N3 / 256, S_LEN / 256), 512, 0, stream>>>(Hb, WtQ, qkv, S_LEN, N3, HID);
  // qkv[s][2*HID + c] -> Vt[c][s]
  transpose64<<<dim3(HID / 64, S_LEN / 64), 256, 0, stream>>>(qkv, Vt, N3, 2 * HID, S_LEN,
                                                              nullptr);
  rope_prep<<<dim3(S_LEN, NHEAD / 4), 256, 0, stream>>>(qkv, pos, Qh, Kh);
  attn_fused<<<dim3(16, NHEAD), 512, 0, stream>>>(Qh, Kh, Vt, AO);
  gemm128c<<<dim3(HID / 128, S_LEN / 128), 256, 0, stream>>>(AO, WtO, d_out, S_LEN, HID,
                                                             HID, flag);
}